// Round 16
// baseline (314.931 us; speedup 1.0000x reference)
//
#include <hip/hip_runtime.h>
#include <hip/hip_bf16.h>
#include <math.h>

using bf16 = __hip_bfloat16;
typedef __attribute__((ext_vector_type(8))) short short8;
typedef __attribute__((ext_vector_type(4))) float float4v;
typedef __attribute__((ext_vector_type(4))) unsigned short ushort4v;

#define DEVI __device__ __forceinline__

constexpr int Nc = 98;
constexpr int NWIN = 256;
constexpr int BNc = 4 * NWIN;           // 1024 windows
constexpr int NTOK = 4 * 8 * 56 * 56;   // 100352 tokens

DEVI float b2f(bf16 v) { return __bfloat162float(v); }
DEVI short f2bs(float v) { bf16 h = __float2bfloat16(v); return *reinterpret_cast<short*>(&h); }

DEVI float4v mfma16(short8 a, short8 b, float4v c) {
    return __builtin_amdgcn_mfma_f32_16x16x32_bf16(a, b, c, 0, 0, 0);
}

DEVI float gelu_tanh(float x) {
    float t = 0.7978845608028654f * (x + 0.044715f * x * x * x);
    float at = fabsf(t);
    float e2 = __expf(-2.0f * at);
    float th = (1.0f - e2) / (1.0f + e2);
    th = copysignf(th, t);
    return 0.5f * x * (1.0f + th);
}

DEVI void gload16(const short* g, short* lds_base) {
    __builtin_amdgcn_global_load_lds((const __attribute__((address_space(1))) unsigned int*)g,
                                     (__attribute__((address_space(3))) unsigned int*)lds_base,
                                     16, 0, 0);
}

// ---------------- K0a: weights fp32 -> bf16 (qkv|proj|fc1|fc2 packed) ----------------
__global__ __launch_bounds__(256) void k_wconv(const float* __restrict__ qw, const float* __restrict__ pw,
                                               const float* __restrict__ f1, const float* __restrict__ f2,
                                               short* __restrict__ wbf) {
    int i = blockIdx.x * 256 + threadIdx.x;           // 196608 total
    float v;
    if (i < 49152) v = qw[i];
    else if (i < 65536) v = pw[i - 49152];
    else if (i < 131072) v = f1[i - 65536];
    else v = f2[i - 131072];
    wbf[i] = f2bs(v);
}

// ---------------- K0b: combined bias+mask table, transposed ----------------
__global__ __launch_bounds__(256) void k_cmb(const int* __restrict__ relidx, const float* __restrict__ rpb,
                                             const float* __restrict__ mask, short* __restrict__ cmbT) {
    int elem = blockIdx.x * 256 + threadIdx.x;        // [0,12544)
    int sl = blockIdx.y;                              // wc*4+head
    int wc = sl >> 2, head = sl & 3;
    int j = elem / 112, i = elem - j * 112;
    float v;
    if (j >= 98)      v = -1e30f;
    else if (i >= 98) v = 0.f;
    else              v = rpb[relidx[i * 98 + j] * 4 + head] + mask[(size_t)wc * 9604 + i * 98 + j];
    cmbT[(size_t)sl * 12544 + elem] = f2bs(v);
}

// ---------------- K2: fused LN1 + cyclic shift + window partition + qkv GEMM ----------------
// grid (3, 784): n-block fastest so one m-tile's 3 n-blocks share x rows in L2.
// Thread t owns A row r=t>>1, cols (t&1)*64..+64: gathers fp32, pair-shuffle LN, bf16 -> swizzled sA.
// W staged async via global_load_lds. Then single-shot 64-MFMA + bounce epilogue.
__global__ __launch_bounds__(256) void k_qkv_ln(const float* __restrict__ x,
                                                const short* __restrict__ Bw,
                                                const float* __restrict__ bias,
                                                const float* __restrict__ g,
                                                const float* __restrict__ bta,
                                                bf16* __restrict__ out) {
    __shared__ __align__(16) short smem[2 * 128 * 128];   // sA 32KB | sB 32KB; bounce overlay [128][136]
    short* sA = smem;
    short* sB = smem + 16384;
    int t = threadIdx.x, lane = t & 63, wid = t >> 6;
    int wm = wid >> 1, wn = wid & 1;
    int n0 = blockIdx.x * 128, m0 = blockIdx.y * 128;

    // ---- issue W (async, 8 gload16/thread = 2048 chunks) ----
    #pragma unroll
    for (int v = 0; v < 8; ++v) {
        int u = v * 256 + wid * 64 + lane;
        int row = u >> 4, csl = u & 15;
        int ch = csl ^ (row & 7);
        gload16(Bw + (size_t)(n0 + row) * 128 + ch * 8, sB + (v * 256 + wid * 64) * 8);
    }

    // ---- A: gather + LN (each thread: its own row's source token) ----
    int r = t >> 1, c0 = (t & 1) * 64;
    {
        int wr = m0 + r;
        int win = wr / 98, n = wr - win * 98;
        int bb = win >> 8, rem = win & 255;
        int dblk = rem >> 6, hblk = (rem >> 3) & 7, wblk = rem & 7;
        int wd = n / 49, r49 = n - wd * 49, wh = r49 / 7, ww = r49 - wh * 7;
        int d = dblk * 2 + wd + 1; if (d >= 8)  d -= 8;     // shift source
        int h = hblk * 7 + wh + 3; if (h >= 56) h -= 56;
        int w = wblk * 7 + ww + 3; if (w >= 56) w -= 56;
        size_t src = ((((size_t)bb * 8 + d) * 56 + h) * 56 + w) * 128 + c0;

        float vals[64];
        float s = 0.f, sq = 0.f;
        #pragma unroll
        for (int j = 0; j < 16; ++j) {
            float4 v4 = *reinterpret_cast<const float4*>(x + src + j * 4);
            vals[j * 4 + 0] = v4.x; vals[j * 4 + 1] = v4.y;
            vals[j * 4 + 2] = v4.z; vals[j * 4 + 3] = v4.w;
            s  += v4.x + v4.y + v4.z + v4.w;
            sq += v4.x * v4.x + v4.y * v4.y + v4.z * v4.z + v4.w * v4.w;
        }
        s += __shfl_xor(s, 1); sq += __shfl_xor(sq, 1);
        float mean = s * (1.0f / 128.0f);
        float var  = sq * (1.0f / 128.0f) - mean * mean;
        float inv  = rsqrtf(var + 1e-5f);
        #pragma unroll
        for (int j = 0; j < 8; ++j) {
            float4 g0 = *reinterpret_cast<const float4*>(g + c0 + j * 8);
            float4 g1 = *reinterpret_cast<const float4*>(g + c0 + j * 8 + 4);
            float4 b0 = *reinterpret_cast<const float4*>(bta + c0 + j * 8);
            float4 b1 = *reinterpret_cast<const float4*>(bta + c0 + j * 8 + 4);
            float gv[8] = {g0.x, g0.y, g0.z, g0.w, g1.x, g1.y, g1.z, g1.w};
            float bv[8] = {b0.x, b0.y, b0.z, b0.w, b1.x, b1.y, b1.z, b1.w};
            short8 pk;
            #pragma unroll
            for (int e = 0; e < 8; ++e)
                pk[e] = f2bs((vals[j * 8 + e] - mean) * inv * gv[e] + bv[e]);
            int ch = (t & 1) * 8 + j;
            *reinterpret_cast<short8*>(&sA[r * 128 + (ch ^ (r & 7)) * 8]) = pk;
        }
    }
    __syncthreads();                                  // drains vmcnt too: W landed

    // ---- 64 MFMA per wave over K=128 ----
    float4v acc[4][4];
    #pragma unroll
    for (int a = 0; a < 4; ++a)
        #pragma unroll
        for (int b = 0; b < 4; ++b) acc[a][b] = (float4v){0.f, 0.f, 0.f, 0.f};
    #pragma unroll
    for (int kc = 0; kc < 4; ++kc) {
        int crb = kc * 4 + (lane >> 4);
        short8 af[4], bfr[4];
        #pragma unroll
        for (int mf = 0; mf < 4; ++mf) {
            int row = wm * 64 + mf * 16 + (lane & 15);
            af[mf] = *reinterpret_cast<const short8*>(&sA[row * 128 + (crb ^ (row & 7)) * 8]);
        }
        #pragma unroll
        for (int nf = 0; nf < 4; ++nf) {
            int row = wn * 64 + nf * 16 + (lane & 15);
            bfr[nf] = *reinterpret_cast<const short8*>(&sB[row * 128 + (crb ^ (row & 7)) * 8]);
        }
        #pragma unroll
        for (int mf = 0; mf < 4; ++mf)
            #pragma unroll
            for (int nf = 0; nf < 4; ++nf)
                acc[mf][nf] = mfma16(af[mf], bfr[nf], acc[mf][nf]);
    }
    __syncthreads();

    // ---- epilogue: bounce [128][136] -> 16B stores; scale Q (cols<128 => blockIdx.x==0) ----
    #pragma unroll
    for (int nf = 0; nf < 4; ++nf) {
        int col = wn * 64 + nf * 16 + (lane & 15);
        float bv = bias[n0 + col];
        #pragma unroll
        for (int mf = 0; mf < 4; ++mf) {
            #pragma unroll
            for (int rr = 0; rr < 4; ++rr) {
                int row = wm * 64 + mf * 16 + (lane >> 4) * 4 + rr;
                float v = acc[mf][nf][rr] + bv;
                if (blockIdx.x == 0) v *= 0.17677669529663689f;
                smem[row * 136 + col] = f2bs(v);
            }
        }
    }
    __syncthreads();
    #pragma unroll
    for (int p = 0; p < 8; ++p) {
        int row = p * 16 + (t >> 4);
        int c8 = (t & 15) * 8;
        uint4 val = *reinterpret_cast<const uint4*>(&smem[row * 136 + c8]);
        *reinterpret_cast<uint4*>(out + (size_t)(m0 + row) * 384 + n0 + c8) = val;
    }
}

// ---------------- MFMA GEMM template: out = A @ W^T + bias ----------------
// EPI: 2 = gelu(tanh) bf16 out via bounce; 3 = +residual(bf16) fp32 out direct.
template<int K, int EPI, typename OutT>
__global__ __launch_bounds__(256) void k_gemm_mfma(const short* __restrict__ A,
                                                   const short* __restrict__ Bw,
                                                   const float* __restrict__ bias,
                                                   const bf16* __restrict__ res,
                                                   OutT* __restrict__ out, int Ncols) {
    __shared__ __align__(16) short smem[128 * 136];
    short* sA = smem;
    short* sB = smem + 8192;
    int t = threadIdx.x;
    int lane = t & 63, wid = t >> 6;
    int wm = wid >> 1, wn = wid & 1;
    int rsub = lane >> 3;
    int csl  = lane & 7;
    int m0 = blockIdx.x * 128, n0 = blockIdx.y * 128;
    float4v acc[4][4];
    #pragma unroll
    for (int a = 0; a < 4; ++a)
        #pragma unroll
        for (int b = 0; b < 4; ++b) acc[a][b] = (float4v){0.f, 0.f, 0.f, 0.f};

    for (int k0 = 0; k0 < K; k0 += 64) {
        #pragma unroll
        for (int v = 0; v < 4; ++v) {
            int row = (wid * 4 + v) * 8 + rsub;
            int ch = csl ^ (row & 7);
            gload16(A + (size_t)(m0 + row) * K + k0 + ch * 8, sA + (wid * 4 + v) * 512);
            gload16(Bw + (size_t)(n0 + row) * K + k0 + ch * 8, sB + (wid * 4 + v) * 512);
        }
        __syncthreads();
        #pragma unroll
        for (int kk = 0; kk < 2; ++kk) {
            int crb = kk * 4 + (lane >> 4);
            short8 af[4], bfr[4];
            #pragma unroll
            for (int mf = 0; mf < 4; ++mf) {
                int row = wm * 64 + mf * 16 + (lane & 15);
                af[mf] = *reinterpret_cast<const short8*>(&sA[row * 64 + (crb ^ (row & 7)) * 8]);
            }
            #pragma unroll
            for (int nf = 0; nf < 4; ++nf) {
                int row = wn * 64 + nf * 16 + (lane & 15);
                bfr[nf] = *reinterpret_cast<const short8*>(&sB[row * 64 + (crb ^ (row & 7)) * 8]);
            }
            #pragma unroll
            for (int mf = 0; mf < 4; ++mf)
                #pragma unroll
                for (int nf = 0; nf < 4; ++nf)
                    acc[mf][nf] = mfma16(af[mf], bfr[nf], acc[mf][nf]);
        }
        __syncthreads();
    }
    if constexpr (sizeof(OutT) == 2) {
        #pragma unroll
        for (int nf = 0; nf < 4; ++nf) {
            int col = wn * 64 + nf * 16 + (lane & 15);
            float bv = bias[n0 + col];
            #pragma unroll
            for (int mf = 0; mf < 4; ++mf) {
                #pragma unroll
                for (int r = 0; r < 4; ++r) {
                    int row = wm * 64 + mf * 16 + (lane >> 4) * 4 + r;
                    float v = acc[mf][nf][r] + bv;
                    if (EPI == 2) v = gelu_tanh(v);
                    smem[row * 136 + col] = f2bs(v);
                }
            }
        }
        __syncthreads();
        #pragma unroll
        for (int p = 0; p < 8; ++p) {
            int row = p * 16 + (t >> 4);
            int c0 = (t & 15) * 8;
            uint4 val = *reinterpret_cast<const uint4*>(&smem[row * 136 + c0]);
            *reinterpret_cast<uint4*>(out + (size_t)(m0 + row) * Ncols + n0 + c0) = val;
        }
    } else {
        #pragma unroll
        for (int mf = 0; mf < 4; ++mf) {
            #pragma unroll
            for (int nf = 0; nf < 4; ++nf) {
                int col = n0 + wn * 64 + nf * 16 + (lane & 15);
                float bvv = bias[col];
                #pragma unroll
                for (int r = 0; r < 4; ++r) {
                    size_t row = m0 + wm * 64 + mf * 16 + (lane >> 4) * 4 + r;
                    float v = acc[mf][nf][r] + bvv;
                    if (EPI == 3) v += b2f(res[row * 128 + col]);
                    out[row * Ncols + col] = v;
                }
            }
        }
    }
}

// ---------------- proj GEMM + window-reverse + residual + LN2 fused ----------------
// x1 now bf16 (residual stream), xn2 bf16.
__global__ __launch_bounds__(256) void k_proj_fused(const short* __restrict__ A,
                                                    const short* __restrict__ Bw,
                                                    const float* __restrict__ bias,
                                                    const float* __restrict__ x,
                                                    const float* __restrict__ g,
                                                    const float* __restrict__ bta,
                                                    bf16* __restrict__ x1,
                                                    bf16* __restrict__ xn2) {
    __shared__ __align__(16) short smem[128 * 136];
    short* sA = smem;
    short* sB = smem + 8192;
    int t = threadIdx.x;
    int lane = t & 63, wid = t >> 6;
    int wm = wid >> 1, wn = wid & 1;
    int rsub = lane >> 3, csl = lane & 7;
    int m0 = blockIdx.x * 128;
    float4v acc[4][4];
    #pragma unroll
    for (int a = 0; a < 4; ++a)
        #pragma unroll
        for (int b = 0; b < 4; ++b) acc[a][b] = (float4v){0.f, 0.f, 0.f, 0.f};

    for (int k0 = 0; k0 < 128; k0 += 64) {
        #pragma unroll
        for (int v = 0; v < 4; ++v) {
            int row = (wid * 4 + v) * 8 + rsub;
            int ch = csl ^ (row & 7);
            gload16(A + (size_t)(m0 + row) * 128 + k0 + ch * 8, sA + (wid * 4 + v) * 512);
            gload16(Bw + (size_t)row * 128 + k0 + ch * 8, sB + (wid * 4 + v) * 512);
        }
        __syncthreads();
        #pragma unroll
        for (int kk = 0; kk < 2; ++kk) {
            int crb = kk * 4 + (lane >> 4);
            short8 af[4], bfr[4];
            #pragma unroll
            for (int mf = 0; mf < 4; ++mf) {
                int row = wm * 64 + mf * 16 + (lane & 15);
                af[mf] = *reinterpret_cast<const short8*>(&sA[row * 64 + (crb ^ (row & 7)) * 8]);
            }
            #pragma unroll
            for (int nf = 0; nf < 4; ++nf) {
                int row = wn * 64 + nf * 16 + (lane & 15);
                bfr[nf] = *reinterpret_cast<const short8*>(&sB[row * 64 + (crb ^ (row & 7)) * 8]);
            }
            #pragma unroll
            for (int mf = 0; mf < 4; ++mf)
                #pragma unroll
                for (int nf = 0; nf < 4; ++nf)
                    acc[mf][nf] = mfma16(af[mf], bfr[nf], acc[mf][nf]);
        }
        __syncthreads();
    }

    int*   tokmap = (int*)smem;
    float* psum   = (float*)(smem + 256);
    float* psq    = (float*)(smem + 768);
    if (t < 128) {
        int wr2 = m0 + t;
        int win = wr2 / 98, n = wr2 - win * 98;
        int bb = win >> 8, rem = win & 255;
        int dblk = rem >> 6, hblk = (rem >> 3) & 7, wblk = rem & 7;
        int wd = n / 49, r49 = n - wd * 49, wh = r49 / 7, ww = r49 - wh * 7;
        int d = dblk * 2 + wd, h = hblk * 7 + wh, w = wblk * 7 + ww;
        int dd = d + 1;  if (dd >= 8)  dd -= 8;
        int hh = h + 3;  if (hh >= 56) hh -= 56;
        int w2 = w + 3;  if (w2 >= 56) w2 -= 56;
        tokmap[t] = ((bb * 8 + dd) * 56 + hh) * 56 + w2;
    }
    __syncthreads();

    #pragma unroll
    for (int mf = 0; mf < 4; ++mf) {
        #pragma unroll
        for (int r = 0; r < 4; ++r) {
            int row = wm * 64 + mf * 16 + (lane >> 4) * 4 + r;
            int tok = tokmap[row];
            float s = 0.f, sq = 0.f;
            #pragma unroll
            for (int nf = 0; nf < 4; ++nf) {
                int col = wn * 64 + nf * 16 + (lane & 15);
                float vv = acc[mf][nf][r] + bias[col] + x[(size_t)tok * 128 + col];
                acc[mf][nf][r] = vv;
                s += vv; sq += vv * vv;
            }
            #pragma unroll
            for (int m = 1; m <= 8; m <<= 1) { s += __shfl_xor(s, m); sq += __shfl_xor(sq, m); }
            if ((lane & 15) == 0) { psum[row * 2 + wn] = s; psq[row * 2 + wn] = sq; }
        }
    }
    __syncthreads();
    #pragma unroll
    for (int mf = 0; mf < 4; ++mf) {
        #pragma unroll
        for (int r = 0; r < 4; ++r) {
            int row = wm * 64 + mf * 16 + (lane >> 4) * 4 + r;
            int tok = tokmap[row];
            float s  = psum[row * 2] + psum[row * 2 + 1];
            float sq = psq[row * 2]  + psq[row * 2 + 1];
            float mean = s * (1.0f / 128.0f);
            float var  = sq * (1.0f / 128.0f) - mean * mean;
            float inv  = rsqrtf(var + 1e-5f);
            #pragma unroll
            for (int nf = 0; nf < 4; ++nf) {
                int col = wn * 64 + nf * 16 + (lane & 15);
                float vv = acc[mf][nf][r];
                x1[(size_t)tok * 128 + col] = __float2bfloat16(vv);
                xn2[(size_t)tok * 128 + col] = __float2bfloat16((vv - mean) * inv * g[col] + bta[col]);
            }
        }
    }
}

// ---------------- K3: MFMA window attention ----------------
__global__ __launch_bounds__(256, 4) void k_attn_mfma(const bf16* __restrict__ qkv,
                                                      const short* __restrict__ cmbT,
                                                      bf16* __restrict__ aout) {
    constexpr int QP = 40;
    constexpr int VP = 136;
    constexpr int PP = 136;
    __shared__ __align__(16) char smem[8704 + 30464];
    short* sVT = (short*)smem;
    short* sQ  = (short*)(smem + 8704);
    short* sK  = (short*)(smem + 8704 + 8960);
    short* sP  = (short*)(smem + 8704);
    int t = threadIdx.x, lane = t & 63, wid = t >> 6;
    int win = blockIdx.x >> 2, head = blockIdx.x & 3;
    const bf16* base = qkv + (size_t)win * Nc * 384 + head * 32;

    for (int idx = t; idx < Nc * 4; idx += 256) {
        int i = idx >> 2, g = idx & 3;
        uint4 q4 = *reinterpret_cast<const uint4*>(base + (size_t)i * 384 + g * 8);
        uint4 k4 = *reinterpret_cast<const uint4*>(base + (size_t)i * 384 + 128 + g * 8);
        uint4 v4 = *reinterpret_cast<const uint4*>(base + (size_t)i * 384 + 256 + g * 8);
        *reinterpret_cast<uint4*>(&sQ[i * QP + g * 8]) = q4;
        *reinterpret_cast<uint4*>(&sK[i * QP + g * 8]) = k4;
        const short* vp = reinterpret_cast<const short*>(&v4);
        #pragma unroll
        for (int e = 0; e < 8; ++e) sVT[(g * 8 + e) * VP + i] = vp[e];
    }
    for (int idx = t; idx < 14 * QP; idx += 256) {
        int r = 98 + idx / QP, c = idx % QP;
        sQ[r * QP + c] = 0; sK[r * QP + c] = 0;
    }
    for (int idx = t; idx < 32 * 30; idx += 256) {
        int d = idx / 30, c = 98 + idx % 30;
        sVT[d * VP + c] = 0;
    }
    __syncthreads();

    float4v s[2][7];
    #pragma unroll
    for (int mi = 0; mi < 2; ++mi)
        #pragma unroll
        for (int fn = 0; fn < 7; ++fn) s[mi][fn] = (float4v){0.f, 0.f, 0.f, 0.f};
    short8 qf[2];
    #pragma unroll
    for (int mi = 0; mi < 2; ++mi) {
        if (wid * 2 + mi < 7) {
            int row = (wid * 2 + mi) * 16 + (lane & 15);
            qf[mi] = *reinterpret_cast<const short8*>(&sQ[row * QP + (lane >> 4) * 8]);
        }
    }
    #pragma unroll
    for (int fn = 0; fn < 7; ++fn) {
        short8 kf = *reinterpret_cast<const short8*>(&sK[(fn * 16 + (lane & 15)) * QP + (lane >> 4) * 8]);
        #pragma unroll
        for (int mi = 0; mi < 2; ++mi) {
            if (wid * 2 + mi < 7) s[mi][fn] = mfma16(qf[mi], kf, s[mi][fn]);
        }
    }

    const unsigned short* cb = (const unsigned short*)(cmbT + (size_t)((win & 255) * 4 + head) * 12544);
    #pragma unroll
    for (int mi = 0; mi < 2; ++mi) {
        if (wid * 2 + mi >= 7) continue;
        int i0 = (wid * 2 + mi) * 16 + (lane >> 4) * 4;
        #pragma unroll
        for (int fn = 0; fn < 7; ++fn) {
            int j = fn * 16 + (lane & 15);
            ushort4v bm4 = *reinterpret_cast<const ushort4v*>(cb + j * 112 + i0);
            #pragma unroll
            for (int r = 0; r < 4; ++r) {
                union { unsigned u; float f; } cv; cv.u = ((unsigned)bm4[r]) << 16;
                s[mi][fn][r] = __expf(s[mi][fn][r] + cv.f);
            }
        }
        #pragma unroll
        for (int r = 0; r < 4; ++r) {
            float sum = 0.f;
            #pragma unroll
            for (int fn = 0; fn < 7; ++fn) sum += s[mi][fn][r];
            #pragma unroll
            for (int m = 1; m <= 8; m <<= 1) sum += __shfl_xor(sum, m);
            float inv = 1.0f / sum;
            #pragma unroll
            for (int fn = 0; fn < 7; ++fn) s[mi][fn][r] *= inv;
        }
    }
    __syncthreads();

    for (int idx = t; idx < 112 * 16; idx += 256) {
        int rr = idx >> 4, c2 = 112 + (idx & 15);
        sP[rr * PP + c2] = 0;
    }
    #pragma unroll
    for (int mi = 0; mi < 2; ++mi) {
        if (wid * 2 + mi >= 7) continue;
        int i0 = (wid * 2 + mi) * 16 + (lane >> 4) * 4;
        #pragma unroll
        for (int r = 0; r < 4; ++r) {
            #pragma unroll
            for (int fn = 0; fn < 7; ++fn) {
                int j = fn * 16 + (lane & 15);
                sP[(i0 + r) * PP + j] = f2bs(s[mi][fn][r]);
            }
        }
    }
    __syncthreads();

    float4v o[2][2];
    #pragma unroll
    for (int mi = 0; mi < 2; ++mi)
        #pragma unroll
        for (int nd = 0; nd < 2; ++nd) o[mi][nd] = (float4v){0.f, 0.f, 0.f, 0.f};
    #pragma unroll
    for (int jc = 0; jc < 4; ++jc) {
        short8 pf[2];
        #pragma unroll
        for (int mi = 0; mi < 2; ++mi) {
            if (wid * 2 + mi < 7) {
                int row = (wid * 2 + mi) * 16 + (lane & 15);
                pf[mi] = *reinterpret_cast<const short8*>(&sP[row * PP + jc * 32 + (lane >> 4) * 8]);
            }
        }
        #pragma unroll
        for (int nd = 0; nd < 2; ++nd) {
            short8 vf = *reinterpret_cast<const short8*>(&sVT[(nd * 16 + (lane & 15)) * VP + jc * 32 + (lane >> 4) * 8]);
            #pragma unroll
            for (int mi = 0; mi < 2; ++mi) {
                if (wid * 2 + mi < 7) o[mi][nd] = mfma16(pf[mi], vf, o[mi][nd]);
            }
        }
    }
    bf16* obase = aout + (size_t)win * Nc * 128 + head * 32;
    #pragma unroll
    for (int mi = 0; mi < 2; ++mi) {
        if (wid * 2 + mi >= 7) continue;
        #pragma unroll
        for (int nd = 0; nd < 2; ++nd) {
            int d = nd * 16 + (lane & 15);
            #pragma unroll
            for (int r = 0; r < 4; ++r) {
                int i = (wid * 2 + mi) * 16 + (lane >> 4) * 4 + r;
                if (i < 98) obase[(size_t)i * 128 + d] = __float2bfloat16(o[mi][nd][r]);
            }
        }
    }
}

extern "C" void kernel_launch(void* const* d_in, const int* in_sizes, int n_in,
                              void* d_out, int out_size, void* d_ws, size_t ws_size,
                              hipStream_t stream) {
    const float* x      = (const float*)d_in[0];
    const float* mask   = (const float*)d_in[1];
    const int*   relidx = (const int*)  d_in[2];
    const float* n1g    = (const float*)d_in[3];
    const float* n1b    = (const float*)d_in[4];
    const float* qkv_w  = (const float*)d_in[5];
    const float* qkv_b  = (const float*)d_in[6];
    const float* rpb    = (const float*)d_in[7];
    const float* proj_w = (const float*)d_in[8];
    const float* proj_b = (const float*)d_in[9];
    const float* n2g    = (const float*)d_in[10];
    const float* n2b    = (const float*)d_in[11];
    const float* fc1_w  = (const float*)d_in[12];
    const float* fc1_b  = (const float*)d_in[13];
    const float* fc2_w  = (const float*)d_in[14];
    const float* fc2_b  = (const float*)d_in[15];

    char* ws = (char*)d_ws;
    const size_t MB = 1024 * 1024;
    bf16*  qkv  = (bf16*)(ws + 25 * MB);      // [25, 98.5)   qkv_ln -> attn
    bf16*  aout = (bf16*)(ws + 99 * MB);      // [99, 123.5)  attn -> proj_fused
    short* cmbT = (short*)(ws + 149 * MB);    // [149, 173.5) cmb -> attn
    bf16*  x1   = (bf16*)(ws);                // [0, 24.5)    proj_fused -> fc2 (bf16 residual)
    bf16*  xn2  = (bf16*)(ws + 50 * MB);      // [50, 74.5)   proj_fused -> fc1
    bf16*  h1   = (bf16*)(ws + 75 * MB);      // [75, 173)    fc1 -> fc2 (cmbT dead by then)
    short* wbf  = (short*)(ws + 174 * MB);    // [174, 174.4) whole launch
    float* out  = (float*)d_out;

    const short* wq = wbf;
    const short* wp = wbf + 49152;
    const short* w1 = wbf + 65536;
    const short* w2 = wbf + 131072;

    k_wconv<<<768, 256, 0, stream>>>(qkv_w, proj_w, fc1_w, fc2_w, wbf);
    k_cmb<<<dim3(49, 1024), 256, 0, stream>>>(relidx, rpb, mask, cmbT);
    k_qkv_ln<<<dim3(3, NTOK / 128), 256, 0, stream>>>(x, wq, qkv_b, n1g, n1b, qkv);
    k_attn_mfma<<<BNc * 4, 256, 0, stream>>>(qkv, cmbT, aout);
    k_proj_fused<<<NTOK / 128, 256, 0, stream>>>((const short*)aout, wp, proj_b, x, n2g, n2b, x1, xn2);
    k_gemm_mfma<128, 2, bf16><<<dim3(NTOK / 128, 4), 256, 0, stream>>>((const short*)xn2, w1, fc1_b, nullptr, h1, 512);
    k_gemm_mfma<512, 3, float><<<dim3(NTOK / 128, 1), 256, 0, stream>>>((const short*)h1, w2, fc2_b, x1, out, 128);
}

// Round 17
// 278.049 us; speedup vs baseline: 1.1326x; 1.1326x over previous
//
#include <hip/hip_runtime.h>
#include <hip/hip_bf16.h>
#include <math.h>

using bf16 = __hip_bfloat16;
typedef __attribute__((ext_vector_type(8))) short short8;
typedef __attribute__((ext_vector_type(4))) float float4v;
typedef __attribute__((ext_vector_type(4))) unsigned short ushort4v;

#define DEVI __device__ __forceinline__

constexpr int Nc = 98;
constexpr int NWIN = 256;
constexpr int BNc = 4 * NWIN;           // 1024 windows
constexpr int NTOK = 4 * 8 * 56 * 56;   // 100352 tokens

DEVI float b2f(bf16 v) { return __bfloat162float(v); }
DEVI short f2bs(float v) { bf16 h = __float2bfloat16(v); return *reinterpret_cast<short*>(&h); }

DEVI float4v mfma16(short8 a, short8 b, float4v c) {
    return __builtin_amdgcn_mfma_f32_16x16x32_bf16(a, b, c, 0, 0, 0);
}

DEVI float gelu_tanh(float x) {
    float t = 0.7978845608028654f * (x + 0.044715f * x * x * x);
    float at = fabsf(t);
    float e2 = __expf(-2.0f * at);
    float th = (1.0f - e2) / (1.0f + e2);
    th = copysignf(th, t);
    return 0.5f * x * (1.0f + th);
}

DEVI void gload16(const short* g, short* lds_base) {
    __builtin_amdgcn_global_load_lds((const __attribute__((address_space(1))) unsigned int*)g,
                                     (__attribute__((address_space(3))) unsigned int*)lds_base,
                                     16, 0, 0);
}

// ---------------- K0a: weights fp32 -> bf16 (qkv|proj|fc1|fc2 packed) ----------------
__global__ __launch_bounds__(256) void k_wconv(const float* __restrict__ qw, const float* __restrict__ pw,
                                               const float* __restrict__ f1, const float* __restrict__ f2,
                                               short* __restrict__ wbf) {
    int i = blockIdx.x * 256 + threadIdx.x;           // 196608 total
    float v;
    if (i < 49152) v = qw[i];
    else if (i < 65536) v = pw[i - 49152];
    else if (i < 131072) v = f1[i - 65536];
    else v = f2[i - 131072];
    wbf[i] = f2bs(v);
}

// ---------------- K0b: combined bias+mask table, transposed ----------------
__global__ __launch_bounds__(256) void k_cmb(const int* __restrict__ relidx, const float* __restrict__ rpb,
                                             const float* __restrict__ mask, short* __restrict__ cmbT) {
    int elem = blockIdx.x * 256 + threadIdx.x;        // [0,12544)
    int sl = blockIdx.y;                              // wc*4+head
    int wc = sl >> 2, head = sl & 3;
    int j = elem / 112, i = elem - j * 112;
    float v;
    if (j >= 98)      v = -1e30f;
    else if (i >= 98) v = 0.f;
    else              v = rpb[relidx[i * 98 + j] * 4 + head] + mask[(size_t)wc * 9604 + i * 98 + j];
    cmbT[(size_t)sl * 12544 + elem] = f2bs(v);
}

// ---------------- K1: LN1 + cyclic shift + window partition ----------------
__global__ __launch_bounds__(256) void k_ln1_win(const float* __restrict__ x,
                                                 const float* __restrict__ g,
                                                 const float* __restrict__ bta,
                                                 bf16* __restrict__ xw) {
    int wave = (blockIdx.x * 256 + threadIdx.x) >> 6;
    int lane = threadIdx.x & 63;
    int win = wave / Nc, n = wave % Nc;
    int bb = win >> 8;
    int rem = win & 255;
    int dblk = rem >> 6, hblk = (rem >> 3) & 7, wblk = rem & 7;
    int wd = n / 49, r49 = n % 49, wh = r49 / 7, ww = r49 % 7;
    int d = dblk * 2 + wd, h = hblk * 7 + wh, w = wblk * 7 + ww;
    int ds = d + 1;  if (ds >= 8)  ds -= 8;
    int hs = h + 3;  if (hs >= 56) hs -= 56;
    int wsp = w + 3; if (wsp >= 56) wsp -= 56;
    size_t src = ((((size_t)bb * 8 + ds) * 56 + hs) * 56 + wsp) * 128;
    int c = lane * 2;
    float2 v = *reinterpret_cast<const float2*>(x + src + c);
    float v0 = v.x, v1 = v.y;
    float s = v0 + v1, sq = v0 * v0 + v1 * v1;
    #pragma unroll
    for (int off = 32; off; off >>= 1) { s += __shfl_xor(s, off); sq += __shfl_xor(sq, off); }
    float mean = s * (1.0f / 128.0f);
    float var  = sq * (1.0f / 128.0f) - mean * mean;
    float inv  = rsqrtf(var + 1e-5f);
    size_t dst = (size_t)wave * 128 + c;
    xw[dst]     = __float2bfloat16((v0 - mean) * inv * g[c]     + bta[c]);
    xw[dst + 1] = __float2bfloat16((v1 - mean) * inv * g[c + 1] + bta[c + 1]);
}

// ---------------- MFMA GEMM template: out = A @ W^T + bias ----------------
// EPI: 0 = qkv (scale cols<128), 2 = gelu(tanh) bf16 out, 3 = +residual(bf16) fp32 out.
template<int K, int EPI, typename OutT>
__global__ __launch_bounds__(256) void k_gemm_mfma(const short* __restrict__ A,
                                                   const short* __restrict__ Bw,
                                                   const float* __restrict__ bias,
                                                   const bf16* __restrict__ res,
                                                   OutT* __restrict__ out, int Ncols) {
    __shared__ __align__(16) short smem[128 * 136];   // staging (2x8192) U bf16-epilogue (17408)
    short* sA = smem;
    short* sB = smem + 8192;
    int t = threadIdx.x;
    int lane = t & 63, wid = t >> 6;
    int wm = wid >> 1, wn = wid & 1;
    int rsub = lane >> 3;
    int csl  = lane & 7;
    int m0 = blockIdx.x * 128, n0 = blockIdx.y * 128;
    float4v acc[4][4];
    #pragma unroll
    for (int a = 0; a < 4; ++a)
        #pragma unroll
        for (int b = 0; b < 4; ++b) acc[a][b] = (float4v){0.f, 0.f, 0.f, 0.f};

    for (int k0 = 0; k0 < K; k0 += 64) {
        #pragma unroll
        for (int v = 0; v < 4; ++v) {
            int row = (wid * 4 + v) * 8 + rsub;
            int ch = csl ^ (row & 7);
            gload16(A + (size_t)(m0 + row) * K + k0 + ch * 8, sA + (wid * 4 + v) * 512);
            gload16(Bw + (size_t)(n0 + row) * K + k0 + ch * 8, sB + (wid * 4 + v) * 512);
        }
        __syncthreads();
        #pragma unroll
        for (int kk = 0; kk < 2; ++kk) {
            int crb = kk * 4 + (lane >> 4);
            short8 af[4], bfr[4];
            #pragma unroll
            for (int mf = 0; mf < 4; ++mf) {
                int row = wm * 64 + mf * 16 + (lane & 15);
                af[mf] = *reinterpret_cast<const short8*>(&sA[row * 64 + (crb ^ (row & 7)) * 8]);
            }
            #pragma unroll
            for (int nf = 0; nf < 4; ++nf) {
                int row = wn * 64 + nf * 16 + (lane & 15);
                bfr[nf] = *reinterpret_cast<const short8*>(&sB[row * 64 + (crb ^ (row & 7)) * 8]);
            }
            #pragma unroll
            for (int mf = 0; mf < 4; ++mf)
                #pragma unroll
                for (int nf = 0; nf < 4; ++nf)
                    acc[mf][nf] = mfma16(af[mf], bfr[nf], acc[mf][nf]);
        }
        __syncthreads();
    }
    if constexpr (sizeof(OutT) == 2) {
        // ---- bf16 epilogue: acc -> LDS [128][136] -> 16B global stores ----
        #pragma unroll
        for (int nf = 0; nf < 4; ++nf) {
            int col = wn * 64 + nf * 16 + (lane & 15);
            int gcol = n0 + col;
            float bv = bias[gcol];
            #pragma unroll
            for (int mf = 0; mf < 4; ++mf) {
                #pragma unroll
                for (int r = 0; r < 4; ++r) {
                    int row = wm * 64 + mf * 16 + (lane >> 4) * 4 + r;
                    float v = acc[mf][nf][r] + bv;
                    if (EPI == 0) { if (gcol < 128) v *= 0.17677669529663689f; }
                    else if (EPI == 2) { v = gelu_tanh(v); }
                    smem[row * 136 + col] = f2bs(v);
                }
            }
        }
        __syncthreads();
        #pragma unroll
        for (int p = 0; p < 8; ++p) {
            int row = p * 16 + (t >> 4);
            int c0 = (t & 15) * 8;
            uint4 val = *reinterpret_cast<const uint4*>(&smem[row * 136 + c0]);
            *reinterpret_cast<uint4*>(out + (size_t)(m0 + row) * Ncols + n0 + c0) = val;
        }
    } else {
        // ---- fp32 epilogue (EPI==3): + bias + bf16 residual, direct stores ----
        #pragma unroll
        for (int mf = 0; mf < 4; ++mf) {
            #pragma unroll
            for (int nf = 0; nf < 4; ++nf) {
                int col = n0 + wn * 64 + nf * 16 + (lane & 15);
                float bvv = bias[col];
                #pragma unroll
                for (int r = 0; r < 4; ++r) {
                    size_t row = m0 + wm * 64 + mf * 16 + (lane >> 4) * 4 + r;
                    float v = acc[mf][nf][r] + bvv;
                    if (EPI == 3) v += b2f(res[row * 128 + col]);
                    out[row * Ncols + col] = v;
                }
            }
        }
    }
}

// ---------------- proj GEMM + window-reverse + residual + LN2 fused ----------------
// x1 stored bf16 (residual stream); xn2 bf16.
__global__ __launch_bounds__(256) void k_proj_fused(const short* __restrict__ A,
                                                    const short* __restrict__ Bw,
                                                    const float* __restrict__ bias,
                                                    const float* __restrict__ x,
                                                    const float* __restrict__ g,
                                                    const float* __restrict__ bta,
                                                    bf16* __restrict__ x1,
                                                    bf16* __restrict__ xn2) {
    __shared__ __align__(16) short smem[128 * 136];
    short* sA = smem;
    short* sB = smem + 8192;
    int t = threadIdx.x;
    int lane = t & 63, wid = t >> 6;
    int wm = wid >> 1, wn = wid & 1;
    int rsub = lane >> 3, csl = lane & 7;
    int m0 = blockIdx.x * 128;
    float4v acc[4][4];
    #pragma unroll
    for (int a = 0; a < 4; ++a)
        #pragma unroll
        for (int b = 0; b < 4; ++b) acc[a][b] = (float4v){0.f, 0.f, 0.f, 0.f};

    for (int k0 = 0; k0 < 128; k0 += 64) {
        #pragma unroll
        for (int v = 0; v < 4; ++v) {
            int row = (wid * 4 + v) * 8 + rsub;
            int ch = csl ^ (row & 7);
            gload16(A + (size_t)(m0 + row) * 128 + k0 + ch * 8, sA + (wid * 4 + v) * 512);
            gload16(Bw + (size_t)row * 128 + k0 + ch * 8, sB + (wid * 4 + v) * 512);
        }
        __syncthreads();
        #pragma unroll
        for (int kk = 0; kk < 2; ++kk) {
            int crb = kk * 4 + (lane >> 4);
            short8 af[4], bfr[4];
            #pragma unroll
            for (int mf = 0; mf < 4; ++mf) {
                int row = wm * 64 + mf * 16 + (lane & 15);
                af[mf] = *reinterpret_cast<const short8*>(&sA[row * 64 + (crb ^ (row & 7)) * 8]);
            }
            #pragma unroll
            for (int nf = 0; nf < 4; ++nf) {
                int row = wn * 64 + nf * 16 + (lane & 15);
                bfr[nf] = *reinterpret_cast<const short8*>(&sB[row * 64 + (crb ^ (row & 7)) * 8]);
            }
            #pragma unroll
            for (int mf = 0; mf < 4; ++mf)
                #pragma unroll
                for (int nf = 0; nf < 4; ++nf)
                    acc[mf][nf] = mfma16(af[mf], bfr[nf], acc[mf][nf]);
        }
        __syncthreads();
    }

    int*   tokmap = (int*)smem;
    float* psum   = (float*)(smem + 256);
    float* psq    = (float*)(smem + 768);
    if (t < 128) {
        int wr2 = m0 + t;
        int win = wr2 / 98, n = wr2 - win * 98;
        int bb = win >> 8, rem = win & 255;
        int dblk = rem >> 6, hblk = (rem >> 3) & 7, wblk = rem & 7;
        int wd = n / 49, r49 = n - wd * 49, wh = r49 / 7, ww = r49 - wh * 7;
        int d = dblk * 2 + wd, h = hblk * 7 + wh, w = wblk * 7 + ww;
        int dd = d + 1;  if (dd >= 8)  dd -= 8;
        int hh = h + 3;  if (hh >= 56) hh -= 56;
        int w2 = w + 3;  if (w2 >= 56) w2 -= 56;
        tokmap[t] = ((bb * 8 + dd) * 56 + hh) * 56 + w2;
    }
    __syncthreads();

    #pragma unroll
    for (int mf = 0; mf < 4; ++mf) {
        #pragma unroll
        for (int r = 0; r < 4; ++r) {
            int row = wm * 64 + mf * 16 + (lane >> 4) * 4 + r;
            int tok = tokmap[row];
            float s = 0.f, sq = 0.f;
            #pragma unroll
            for (int nf = 0; nf < 4; ++nf) {
                int col = wn * 64 + nf * 16 + (lane & 15);
                float vv = acc[mf][nf][r] + bias[col] + x[(size_t)tok * 128 + col];
                acc[mf][nf][r] = vv;
                s += vv; sq += vv * vv;
            }
            #pragma unroll
            for (int m = 1; m <= 8; m <<= 1) { s += __shfl_xor(s, m); sq += __shfl_xor(sq, m); }
            if ((lane & 15) == 0) { psum[row * 2 + wn] = s; psq[row * 2 + wn] = sq; }
        }
    }
    __syncthreads();
    #pragma unroll
    for (int mf = 0; mf < 4; ++mf) {
        #pragma unroll
        for (int r = 0; r < 4; ++r) {
            int row = wm * 64 + mf * 16 + (lane >> 4) * 4 + r;
            int tok = tokmap[row];
            float s  = psum[row * 2] + psum[row * 2 + 1];
            float sq = psq[row * 2]  + psq[row * 2 + 1];
            float mean = s * (1.0f / 128.0f);
            float var  = sq * (1.0f / 128.0f) - mean * mean;
            float inv  = rsqrtf(var + 1e-5f);
            #pragma unroll
            for (int nf = 0; nf < 4; ++nf) {
                int col = wn * 64 + nf * 16 + (lane & 15);
                float vv = acc[mf][nf][r];
                x1[(size_t)tok * 128 + col] = __float2bfloat16(vv);
                xn2[(size_t)tok * 128 + col] = __float2bfloat16((vv - mean) * inv * g[col] + bta[col]);
            }
        }
    }
}

// ---------------- K3: MFMA window attention ----------------
__global__ __launch_bounds__(256, 4) void k_attn_mfma(const bf16* __restrict__ qkv,
                                                      const short* __restrict__ cmbT,
                                                      bf16* __restrict__ aout) {
    constexpr int QP = 40;
    constexpr int VP = 136;
    constexpr int PP = 136;
    __shared__ __align__(16) char smem[8704 + 30464];
    short* sVT = (short*)smem;
    short* sQ  = (short*)(smem + 8704);
    short* sK  = (short*)(smem + 8704 + 8960);
    short* sP  = (short*)(smem + 8704);
    int t = threadIdx.x, lane = t & 63, wid = t >> 6;
    int win = blockIdx.x >> 2, head = blockIdx.x & 3;
    const bf16* base = qkv + (size_t)win * Nc * 384 + head * 32;

    for (int idx = t; idx < Nc * 4; idx += 256) {
        int i = idx >> 2, g = idx & 3;
        uint4 q4 = *reinterpret_cast<const uint4*>(base + (size_t)i * 384 + g * 8);
        uint4 k4 = *reinterpret_cast<const uint4*>(base + (size_t)i * 384 + 128 + g * 8);
        uint4 v4 = *reinterpret_cast<const uint4*>(base + (size_t)i * 384 + 256 + g * 8);
        *reinterpret_cast<uint4*>(&sQ[i * QP + g * 8]) = q4;
        *reinterpret_cast<uint4*>(&sK[i * QP + g * 8]) = k4;
        const short* vp = reinterpret_cast<const short*>(&v4);
        #pragma unroll
        for (int e = 0; e < 8; ++e) sVT[(g * 8 + e) * VP + i] = vp[e];
    }
    for (int idx = t; idx < 14 * QP; idx += 256) {
        int r = 98 + idx / QP, c = idx % QP;
        sQ[r * QP + c] = 0; sK[r * QP + c] = 0;
    }
    for (int idx = t; idx < 32 * 30; idx += 256) {
        int d = idx / 30, c = 98 + idx % 30;
        sVT[d * VP + c] = 0;
    }
    __syncthreads();

    float4v s[2][7];
    #pragma unroll
    for (int mi = 0; mi < 2; ++mi)
        #pragma unroll
        for (int fn = 0; fn < 7; ++fn) s[mi][fn] = (float4v){0.f, 0.f, 0.f, 0.f};
    short8 qf[2];
    #pragma unroll
    for (int mi = 0; mi < 2; ++mi) {
        if (wid * 2 + mi < 7) {
            int row = (wid * 2 + mi) * 16 + (lane & 15);
            qf[mi] = *reinterpret_cast<const short8*>(&sQ[row * QP + (lane >> 4) * 8]);
        }
    }
    #pragma unroll
    for (int fn = 0; fn < 7; ++fn) {
        short8 kf = *reinterpret_cast<const short8*>(&sK[(fn * 16 + (lane & 15)) * QP + (lane >> 4) * 8]);
        #pragma unroll
        for (int mi = 0; mi < 2; ++mi) {
            if (wid * 2 + mi < 7) s[mi][fn] = mfma16(qf[mi], kf, s[mi][fn]);
        }
    }

    const unsigned short* cb = (const unsigned short*)(cmbT + (size_t)((win & 255) * 4 + head) * 12544);
    #pragma unroll
    for (int mi = 0; mi < 2; ++mi) {
        if (wid * 2 + mi >= 7) continue;
        int i0 = (wid * 2 + mi) * 16 + (lane >> 4) * 4;
        #pragma unroll
        for (int fn = 0; fn < 7; ++fn) {
            int j = fn * 16 + (lane & 15);
            ushort4v bm4 = *reinterpret_cast<const ushort4v*>(cb + j * 112 + i0);
            #pragma unroll
            for (int r = 0; r < 4; ++r) {
                union { unsigned u; float f; } cv; cv.u = ((unsigned)bm4[r]) << 16;
                s[mi][fn][r] = __expf(s[mi][fn][r] + cv.f);
            }
        }
        #pragma unroll
        for (int r = 0; r < 4; ++r) {
            float sum = 0.f;
            #pragma unroll
            for (int fn = 0; fn < 7; ++fn) sum += s[mi][fn][r];
            #pragma unroll
            for (int m = 1; m <= 8; m <<= 1) sum += __shfl_xor(sum, m);
            float inv = 1.0f / sum;
            #pragma unroll
            for (int fn = 0; fn < 7; ++fn) s[mi][fn][r] *= inv;
        }
    }
    __syncthreads();

    for (int idx = t; idx < 112 * 16; idx += 256) {
        int rr = idx >> 4, c2 = 112 + (idx & 15);
        sP[rr * PP + c2] = 0;
    }
    #pragma unroll
    for (int mi = 0; mi < 2; ++mi) {
        if (wid * 2 + mi >= 7) continue;
        int i0 = (wid * 2 + mi) * 16 + (lane >> 4) * 4;
        #pragma unroll
        for (int r = 0; r < 4; ++r) {
            #pragma unroll
            for (int fn = 0; fn < 7; ++fn) {
                int j = fn * 16 + (lane & 15);
                sP[(i0 + r) * PP + j] = f2bs(s[mi][fn][r]);
            }
        }
    }
    __syncthreads();

    float4v o[2][2];
    #pragma unroll
    for (int mi = 0; mi < 2; ++mi)
        #pragma unroll
        for (int nd = 0; nd < 2; ++nd) o[mi][nd] = (float4v){0.f, 0.f, 0.f, 0.f};
    #pragma unroll
    for (int jc = 0; jc < 4; ++jc) {
        short8 pf[2];
        #pragma unroll
        for (int mi = 0; mi < 2; ++mi) {
            if (wid * 2 + mi < 7) {
                int row = (wid * 2 + mi) * 16 + (lane & 15);
                pf[mi] = *reinterpret_cast<const short8*>(&sP[row * PP + jc * 32 + (lane >> 4) * 8]);
            }
        }
        #pragma unroll
        for (int nd = 0; nd < 2; ++nd) {
            short8 vf = *reinterpret_cast<const short8*>(&sVT[(nd * 16 + (lane & 15)) * VP + jc * 32 + (lane >> 4) * 8]);
            #pragma unroll
            for (int mi = 0; mi < 2; ++mi) {
                if (wid * 2 + mi < 7) o[mi][nd] = mfma16(pf[mi], vf, o[mi][nd]);
            }
        }
    }
    bf16* obase = aout + (size_t)win * Nc * 128 + head * 32;
    #pragma unroll
    for (int mi = 0; mi < 2; ++mi) {
        if (wid * 2 + mi >= 7) continue;
        #pragma unroll
        for (int nd = 0; nd < 2; ++nd) {
            int d = nd * 16 + (lane & 15);
            #pragma unroll
            for (int r = 0; r < 4; ++r) {
                int i = (wid * 2 + mi) * 16 + (lane >> 4) * 4 + r;
                if (i < 98) obase[(size_t)i * 128 + d] = __float2bfloat16(o[mi][nd][r]);
            }
        }
    }
}

extern "C" void kernel_launch(void* const* d_in, const int* in_sizes, int n_in,
                              void* d_out, int out_size, void* d_ws, size_t ws_size,
                              hipStream_t stream) {
    const float* x      = (const float*)d_in[0];
    const float* mask   = (const float*)d_in[1];
    const int*   relidx = (const int*)  d_in[2];
    const float* n1g    = (const float*)d_in[3];
    const float* n1b    = (const float*)d_in[4];
    const float* qkv_w  = (const float*)d_in[5];
    const float* qkv_b  = (const float*)d_in[6];
    const float* rpb    = (const float*)d_in[7];
    const float* proj_w = (const float*)d_in[8];
    const float* proj_b = (const float*)d_in[9];
    const float* n2g    = (const float*)d_in[10];
    const float* n2b    = (const float*)d_in[11];
    const float* fc1_w  = (const float*)d_in[12];
    const float* fc1_b  = (const float*)d_in[13];
    const float* fc2_w  = (const float*)d_in[14];
    const float* fc2_b  = (const float*)d_in[15];

    char* ws = (char*)d_ws;
    const size_t MB = 1024 * 1024;
    bf16*  xw   = (bf16*)(ws);                // [0, 24.5)    k1 -> qkvG
    bf16*  qkv  = (bf16*)(ws + 25 * MB);      // [25, 98.5)   qkvG -> attn
    bf16*  aout = (bf16*)(ws + 99 * MB);      // [99, 123.5)  attn -> proj_fused
    short* cmbT = (short*)(ws + 149 * MB);    // [149, 173.5) cmb -> attn
    bf16*  x1   = (bf16*)(ws);                // [0, 24.5)    proj_fused -> fc2 (xw dead; bf16)
    bf16*  xn2  = (bf16*)(ws + 50 * MB);      // [50, 74.5)   proj_fused -> fc1
    bf16*  h1   = (bf16*)(ws + 75 * MB);      // [75, 173)    fc1 -> fc2 (aout/cmbT dead)
    short* wbf  = (short*)(ws + 174 * MB);    // [174, 174.4) whole launch
    float* out  = (float*)d_out;

    const short* wq = wbf;
    const short* wp = wbf + 49152;
    const short* w1 = wbf + 65536;
    const short* w2 = wbf + 131072;

    k_wconv<<<768, 256, 0, stream>>>(qkv_w, proj_w, fc1_w, fc2_w, wbf);
    k_cmb<<<dim3(49, 1024), 256, 0, stream>>>(relidx, rpb, mask, cmbT);
    k_ln1_win<<<NTOK / 4, 256, 0, stream>>>(x, n1g, n1b, xw);
    k_gemm_mfma<128, 0, bf16><<<dim3(NTOK / 128, 3), 256, 0, stream>>>((const short*)xw, wq, qkv_b, nullptr, qkv, 384);
    k_attn_mfma<<<BNc * 4, 256, 0, stream>>>(qkv, cmbT, aout);
    k_proj_fused<<<NTOK / 128, 256, 0, stream>>>((const short*)aout, wp, proj_b, x, n2g, n2b, x1, xn2);
    k_gemm_mfma<128, 2, bf16><<<dim3(NTOK / 128, 4), 256, 0, stream>>>((const short*)xn2, w1, fc1_b, nullptr, h1, 512);
    k_gemm_mfma<512, 3, float><<<dim3(NTOK / 128, 1), 256, 0, stream>>>((const short*)h1, w2, fc2_b, x1, out, 128);
}

// Round 18
// 274.508 us; speedup vs baseline: 1.1473x; 1.0129x over previous
//
#include <hip/hip_runtime.h>
#include <hip/hip_bf16.h>
#include <math.h>

using bf16 = __hip_bfloat16;
typedef __attribute__((ext_vector_type(8))) short short8;
typedef __attribute__((ext_vector_type(4))) float float4v;
typedef __attribute__((ext_vector_type(4))) unsigned short ushort4v;

#define DEVI __device__ __forceinline__

constexpr int Nc = 98;
constexpr int NWIN = 256;
constexpr int BNc = 4 * NWIN;           // 1024 windows
constexpr int NTOK = 4 * 8 * 56 * 56;   // 100352 tokens

DEVI float b2f(bf16 v) { return __bfloat162float(v); }
DEVI short f2bs(float v) { bf16 h = __float2bfloat16(v); return *reinterpret_cast<short*>(&h); }

DEVI float4v mfma16(short8 a, short8 b, float4v c) {
    return __builtin_amdgcn_mfma_f32_16x16x32_bf16(a, b, c, 0, 0, 0);
}

DEVI float gelu_tanh(float x) {
    float t = 0.7978845608028654f * (x + 0.044715f * x * x * x);
    float at = fabsf(t);
    float e2 = __expf(-2.0f * at);
    float th = (1.0f - e2) / (1.0f + e2);
    th = copysignf(th, t);
    return 0.5f * x * (1.0f + th);
}

DEVI void gload16(const short* g, short* lds_base) {
    __builtin_amdgcn_global_load_lds((const __attribute__((address_space(1))) unsigned int*)g,
                                     (__attribute__((address_space(3))) unsigned int*)lds_base,
                                     16, 0, 0);
}

// ---------------- K0a: weights fp32 -> bf16 (qkv|proj|fc1|fc2 packed) ----------------
__global__ __launch_bounds__(256) void k_wconv(const float* __restrict__ qw, const float* __restrict__ pw,
                                               const float* __restrict__ f1, const float* __restrict__ f2,
                                               short* __restrict__ wbf) {
    int i = blockIdx.x * 256 + threadIdx.x;           // 196608 total
    float v;
    if (i < 49152) v = qw[i];
    else if (i < 65536) v = pw[i - 49152];
    else if (i < 131072) v = f1[i - 65536];
    else v = f2[i - 131072];
    wbf[i] = f2bs(v);
}

// ---------------- K0b: combined bias+mask table, transposed ----------------
__global__ __launch_bounds__(256) void k_cmb(const int* __restrict__ relidx, const float* __restrict__ rpb,
                                             const float* __restrict__ mask, short* __restrict__ cmbT) {
    int elem = blockIdx.x * 256 + threadIdx.x;        // [0,12544)
    int sl = blockIdx.y;                              // wc*4+head
    int wc = sl >> 2, head = sl & 3;
    int j = elem / 112, i = elem - j * 112;
    float v;
    if (j >= 98)      v = -1e30f;
    else if (i >= 98) v = 0.f;
    else              v = rpb[relidx[i * 98 + j] * 4 + head] + mask[(size_t)wc * 9604 + i * 98 + j];
    cmbT[(size_t)sl * 12544 + elem] = f2bs(v);
}

// ---------------- K1: LN1 + cyclic shift + window partition ----------------
__global__ __launch_bounds__(256) void k_ln1_win(const float* __restrict__ x,
                                                 const float* __restrict__ g,
                                                 const float* __restrict__ bta,
                                                 bf16* __restrict__ xw) {
    int wave = (blockIdx.x * 256 + threadIdx.x) >> 6;
    int lane = threadIdx.x & 63;
    int win = wave / Nc, n = wave % Nc;
    int bb = win >> 8;
    int rem = win & 255;
    int dblk = rem >> 6, hblk = (rem >> 3) & 7, wblk = rem & 7;
    int wd = n / 49, r49 = n % 49, wh = r49 / 7, ww = r49 % 7;
    int d = dblk * 2 + wd, h = hblk * 7 + wh, w = wblk * 7 + ww;
    int ds = d + 1;  if (ds >= 8)  ds -= 8;
    int hs = h + 3;  if (hs >= 56) hs -= 56;
    int wsp = w + 3; if (wsp >= 56) wsp -= 56;
    size_t src = ((((size_t)bb * 8 + ds) * 56 + hs) * 56 + wsp) * 128;
    int c = lane * 2;
    float2 v = *reinterpret_cast<const float2*>(x + src + c);
    float v0 = v.x, v1 = v.y;
    float s = v0 + v1, sq = v0 * v0 + v1 * v1;
    #pragma unroll
    for (int off = 32; off; off >>= 1) { s += __shfl_xor(s, off); sq += __shfl_xor(sq, off); }
    float mean = s * (1.0f / 128.0f);
    float var  = sq * (1.0f / 128.0f) - mean * mean;
    float inv  = rsqrtf(var + 1e-5f);
    size_t dst = (size_t)wave * 128 + c;
    xw[dst]     = __float2bfloat16((v0 - mean) * inv * g[c]     + bta[c]);
    xw[dst + 1] = __float2bfloat16((v1 - mean) * inv * g[c + 1] + bta[c + 1]);
}

// ---------------- MFMA GEMM template: out = A @ W^T + bias ----------------
// EPI: 0 = qkv (scale cols<128), 2 = gelu(tanh) bf16 out, 3 = +residual(bf16) fp32 out.
// NSWAP: n-tile on blockIdx.x (fastest) so one m-tile's n-blocks are dispatch-adjacent (A L2-hot).
template<int K, int EPI, typename OutT, bool NSWAP>
__global__ __launch_bounds__(256) void k_gemm_mfma(const short* __restrict__ A,
                                                   const short* __restrict__ Bw,
                                                   const float* __restrict__ bias,
                                                   const bf16* __restrict__ res,
                                                   OutT* __restrict__ out, int Ncols) {
    __shared__ __align__(16) short smem[128 * 136];   // staging (2x8192) U bf16-epilogue (17408)
    short* sA = smem;
    short* sB = smem + 8192;
    int t = threadIdx.x;
    int lane = t & 63, wid = t >> 6;
    int wm = wid >> 1, wn = wid & 1;
    int rsub = lane >> 3;
    int csl  = lane & 7;
    int m0 = (NSWAP ? blockIdx.y : blockIdx.x) * 128;
    int n0 = (NSWAP ? blockIdx.x : blockIdx.y) * 128;
    float4v acc[4][4];
    #pragma unroll
    for (int a = 0; a < 4; ++a)
        #pragma unroll
        for (int b = 0; b < 4; ++b) acc[a][b] = (float4v){0.f, 0.f, 0.f, 0.f};

    for (int k0 = 0; k0 < K; k0 += 64) {
        #pragma unroll
        for (int v = 0; v < 4; ++v) {
            int row = (wid * 4 + v) * 8 + rsub;
            int ch = csl ^ (row & 7);
            gload16(A + (size_t)(m0 + row) * K + k0 + ch * 8, sA + (wid * 4 + v) * 512);
            gload16(Bw + (size_t)(n0 + row) * K + k0 + ch * 8, sB + (wid * 4 + v) * 512);
        }
        __syncthreads();
        #pragma unroll
        for (int kk = 0; kk < 2; ++kk) {
            int crb = kk * 4 + (lane >> 4);
            short8 af[4], bfr[4];
            #pragma unroll
            for (int mf = 0; mf < 4; ++mf) {
                int row = wm * 64 + mf * 16 + (lane & 15);
                af[mf] = *reinterpret_cast<const short8*>(&sA[row * 64 + (crb ^ (row & 7)) * 8]);
            }
            #pragma unroll
            for (int nf = 0; nf < 4; ++nf) {
                int row = wn * 64 + nf * 16 + (lane & 15);
                bfr[nf] = *reinterpret_cast<const short8*>(&sB[row * 64 + (crb ^ (row & 7)) * 8]);
            }
            #pragma unroll
            for (int mf = 0; mf < 4; ++mf)
                #pragma unroll
                for (int nf = 0; nf < 4; ++nf)
                    acc[mf][nf] = mfma16(af[mf], bfr[nf], acc[mf][nf]);
        }
        __syncthreads();
    }
    if constexpr (sizeof(OutT) == 2) {
        // ---- bf16 epilogue: acc -> LDS [128][136] -> 16B global stores ----
        #pragma unroll
        for (int nf = 0; nf < 4; ++nf) {
            int col = wn * 64 + nf * 16 + (lane & 15);
            int gcol = n0 + col;
            float bv = bias[gcol];
            #pragma unroll
            for (int mf = 0; mf < 4; ++mf) {
                #pragma unroll
                for (int r = 0; r < 4; ++r) {
                    int row = wm * 64 + mf * 16 + (lane >> 4) * 4 + r;
                    float v = acc[mf][nf][r] + bv;
                    if (EPI == 0) { if (gcol < 128) v *= 0.17677669529663689f; }
                    else if (EPI == 2) { v = gelu_tanh(v); }
                    smem[row * 136 + col] = f2bs(v);
                }
            }
        }
        __syncthreads();
        #pragma unroll
        for (int p = 0; p < 8; ++p) {
            int row = p * 16 + (t >> 4);
            int c0 = (t & 15) * 8;
            uint4 val = *reinterpret_cast<const uint4*>(&smem[row * 136 + c0]);
            *reinterpret_cast<uint4*>(out + (size_t)(m0 + row) * Ncols + n0 + c0) = val;
        }
    } else {
        // ---- fp32 epilogue (EPI==3): + bias + bf16 residual, direct stores ----
        #pragma unroll
        for (int mf = 0; mf < 4; ++mf) {
            #pragma unroll
            for (int nf = 0; nf < 4; ++nf) {
                int col = n0 + wn * 64 + nf * 16 + (lane & 15);
                float bvv = bias[col];
                #pragma unroll
                for (int r = 0; r < 4; ++r) {
                    size_t row = m0 + wm * 64 + mf * 16 + (lane >> 4) * 4 + r;
                    float v = acc[mf][nf][r] + bvv;
                    if (EPI == 3) v += b2f(res[row * 128 + col]);
                    out[row * Ncols + col] = v;
                }
            }
        }
    }
}

// ---------------- proj GEMM + window-reverse + residual + LN2 fused ----------------
__global__ __launch_bounds__(256) void k_proj_fused(const short* __restrict__ A,
                                                    const short* __restrict__ Bw,
                                                    const float* __restrict__ bias,
                                                    const float* __restrict__ x,
                                                    const float* __restrict__ g,
                                                    const float* __restrict__ bta,
                                                    bf16* __restrict__ x1,
                                                    bf16* __restrict__ xn2) {
    __shared__ __align__(16) short smem[128 * 136];
    short* sA = smem;
    short* sB = smem + 8192;
    int t = threadIdx.x;
    int lane = t & 63, wid = t >> 6;
    int wm = wid >> 1, wn = wid & 1;
    int rsub = lane >> 3, csl = lane & 7;
    int m0 = blockIdx.x * 128;
    float4v acc[4][4];
    #pragma unroll
    for (int a = 0; a < 4; ++a)
        #pragma unroll
        for (int b = 0; b < 4; ++b) acc[a][b] = (float4v){0.f, 0.f, 0.f, 0.f};

    for (int k0 = 0; k0 < 128; k0 += 64) {
        #pragma unroll
        for (int v = 0; v < 4; ++v) {
            int row = (wid * 4 + v) * 8 + rsub;
            int ch = csl ^ (row & 7);
            gload16(A + (size_t)(m0 + row) * 128 + k0 + ch * 8, sA + (wid * 4 + v) * 512);
            gload16(Bw + (size_t)row * 128 + k0 + ch * 8, sB + (wid * 4 + v) * 512);
        }
        __syncthreads();
        #pragma unroll
        for (int kk = 0; kk < 2; ++kk) {
            int crb = kk * 4 + (lane >> 4);
            short8 af[4], bfr[4];
            #pragma unroll
            for (int mf = 0; mf < 4; ++mf) {
                int row = wm * 64 + mf * 16 + (lane & 15);
                af[mf] = *reinterpret_cast<const short8*>(&sA[row * 64 + (crb ^ (row & 7)) * 8]);
            }
            #pragma unroll
            for (int nf = 0; nf < 4; ++nf) {
                int row = wn * 64 + nf * 16 + (lane & 15);
                bfr[nf] = *reinterpret_cast<const short8*>(&sB[row * 64 + (crb ^ (row & 7)) * 8]);
            }
            #pragma unroll
            for (int mf = 0; mf < 4; ++mf)
                #pragma unroll
                for (int nf = 0; nf < 4; ++nf)
                    acc[mf][nf] = mfma16(af[mf], bfr[nf], acc[mf][nf]);
        }
        __syncthreads();
    }

    int*   tokmap = (int*)smem;
    float* psum   = (float*)(smem + 256);
    float* psq    = (float*)(smem + 768);
    if (t < 128) {
        int wr2 = m0 + t;
        int win = wr2 / 98, n = wr2 - win * 98;
        int bb = win >> 8, rem = win & 255;
        int dblk = rem >> 6, hblk = (rem >> 3) & 7, wblk = rem & 7;
        int wd = n / 49, r49 = n - wd * 49, wh = r49 / 7, ww = r49 - wh * 7;
        int d = dblk * 2 + wd, h = hblk * 7 + wh, w = wblk * 7 + ww;
        int dd = d + 1;  if (dd >= 8)  dd -= 8;
        int hh = h + 3;  if (hh >= 56) hh -= 56;
        int w2 = w + 3;  if (w2 >= 56) w2 -= 56;
        tokmap[t] = ((bb * 8 + dd) * 56 + hh) * 56 + w2;
    }
    __syncthreads();

    #pragma unroll
    for (int mf = 0; mf < 4; ++mf) {
        #pragma unroll
        for (int r = 0; r < 4; ++r) {
            int row = wm * 64 + mf * 16 + (lane >> 4) * 4 + r;
            int tok = tokmap[row];
            float s = 0.f, sq = 0.f;
            #pragma unroll
            for (int nf = 0; nf < 4; ++nf) {
                int col = wn * 64 + nf * 16 + (lane & 15);
                float vv = acc[mf][nf][r] + bias[col] + x[(size_t)tok * 128 + col];
                acc[mf][nf][r] = vv;
                s += vv; sq += vv * vv;
            }
            #pragma unroll
            for (int m = 1; m <= 8; m <<= 1) { s += __shfl_xor(s, m); sq += __shfl_xor(sq, m); }
            if ((lane & 15) == 0) { psum[row * 2 + wn] = s; psq[row * 2 + wn] = sq; }
        }
    }
    __syncthreads();
    #pragma unroll
    for (int mf = 0; mf < 4; ++mf) {
        #pragma unroll
        for (int r = 0; r < 4; ++r) {
            int row = wm * 64 + mf * 16 + (lane >> 4) * 4 + r;
            int tok = tokmap[row];
            float s  = psum[row * 2] + psum[row * 2 + 1];
            float sq = psq[row * 2]  + psq[row * 2 + 1];
            float mean = s * (1.0f / 128.0f);
            float var  = sq * (1.0f / 128.0f) - mean * mean;
            float inv  = rsqrtf(var + 1e-5f);
            #pragma unroll
            for (int nf = 0; nf < 4; ++nf) {
                int col = wn * 64 + nf * 16 + (lane & 15);
                float vv = acc[mf][nf][r];
                x1[(size_t)tok * 128 + col] = __float2bfloat16(vv);
                xn2[(size_t)tok * 128 + col] = __float2bfloat16((vv - mean) * inv * g[col] + bta[col]);
            }
        }
    }
}

// ---------------- K3: MFMA window attention ----------------
__global__ __launch_bounds__(256, 4) void k_attn_mfma(const bf16* __restrict__ qkv,
                                                      const short* __restrict__ cmbT,
                                                      bf16* __restrict__ aout) {
    constexpr int QP = 40;
    constexpr int VP = 136;
    constexpr int PP = 136;
    __shared__ __align__(16) char smem[8704 + 30464];
    short* sVT = (short*)smem;
    short* sQ  = (short*)(smem + 8704);
    short* sK  = (short*)(smem + 8704 + 8960);
    short* sP  = (short*)(smem + 8704);
    int t = threadIdx.x, lane = t & 63, wid = t >> 6;
    int win = blockIdx.x >> 2, head = blockIdx.x & 3;
    const bf16* base = qkv + (size_t)win * Nc * 384 + head * 32;

    for (int idx = t; idx < Nc * 4; idx += 256) {
        int i = idx >> 2, g = idx & 3;
        uint4 q4 = *reinterpret_cast<const uint4*>(base + (size_t)i * 384 + g * 8);
        uint4 k4 = *reinterpret_cast<const uint4*>(base + (size_t)i * 384 + 128 + g * 8);
        uint4 v4 = *reinterpret_cast<const uint4*>(base + (size_t)i * 384 + 256 + g * 8);
        *reinterpret_cast<uint4*>(&sQ[i * QP + g * 8]) = q4;
        *reinterpret_cast<uint4*>(&sK[i * QP + g * 8]) = k4;
        const short* vp = reinterpret_cast<const short*>(&v4);
        #pragma unroll
        for (int e = 0; e < 8; ++e) sVT[(g * 8 + e) * VP + i] = vp[e];
    }
    for (int idx = t; idx < 14 * QP; idx += 256) {
        int r = 98 + idx / QP, c = idx % QP;
        sQ[r * QP + c] = 0; sK[r * QP + c] = 0;
    }
    for (int idx = t; idx < 32 * 30; idx += 256) {
        int d = idx / 30, c = 98 + idx % 30;
        sVT[d * VP + c] = 0;
    }
    __syncthreads();

    float4v s[2][7];
    #pragma unroll
    for (int mi = 0; mi < 2; ++mi)
        #pragma unroll
        for (int fn = 0; fn < 7; ++fn) s[mi][fn] = (float4v){0.f, 0.f, 0.f, 0.f};
    short8 qf[2];
    #pragma unroll
    for (int mi = 0; mi < 2; ++mi) {
        if (wid * 2 + mi < 7) {
            int row = (wid * 2 + mi) * 16 + (lane & 15);
            qf[mi] = *reinterpret_cast<const short8*>(&sQ[row * QP + (lane >> 4) * 8]);
        }
    }
    #pragma unroll
    for (int fn = 0; fn < 7; ++fn) {
        short8 kf = *reinterpret_cast<const short8*>(&sK[(fn * 16 + (lane & 15)) * QP + (lane >> 4) * 8]);
        #pragma unroll
        for (int mi = 0; mi < 2; ++mi) {
            if (wid * 2 + mi < 7) s[mi][fn] = mfma16(qf[mi], kf, s[mi][fn]);
        }
    }

    const unsigned short* cb = (const unsigned short*)(cmbT + (size_t)((win & 255) * 4 + head) * 12544);
    #pragma unroll
    for (int mi = 0; mi < 2; ++mi) {
        if (wid * 2 + mi >= 7) continue;
        int i0 = (wid * 2 + mi) * 16 + (lane >> 4) * 4;
        #pragma unroll
        for (int fn = 0; fn < 7; ++fn) {
            int j = fn * 16 + (lane & 15);
            ushort4v bm4 = *reinterpret_cast<const ushort4v*>(cb + j * 112 + i0);
            #pragma unroll
            for (int r = 0; r < 4; ++r) {
                union { unsigned u; float f; } cv; cv.u = ((unsigned)bm4[r]) << 16;
                s[mi][fn][r] = __expf(s[mi][fn][r] + cv.f);
            }
        }
        #pragma unroll
        for (int r = 0; r < 4; ++r) {
            float sum = 0.f;
            #pragma unroll
            for (int fn = 0; fn < 7; ++fn) sum += s[mi][fn][r];
            #pragma unroll
            for (int m = 1; m <= 8; m <<= 1) sum += __shfl_xor(sum, m);
            float inv = 1.0f / sum;
            #pragma unroll
            for (int fn = 0; fn < 7; ++fn) s[mi][fn][r] *= inv;
        }
    }
    __syncthreads();

    for (int idx = t; idx < 112 * 16; idx += 256) {
        int rr = idx >> 4, c2 = 112 + (idx & 15);
        sP[rr * PP + c2] = 0;
    }
    #pragma unroll
    for (int mi = 0; mi < 2; ++mi) {
        if (wid * 2 + mi >= 7) continue;
        int i0 = (wid * 2 + mi) * 16 + (lane >> 4) * 4;
        #pragma unroll
        for (int r = 0; r < 4; ++r) {
            #pragma unroll
            for (int fn = 0; fn < 7; ++fn) {
                int j = fn * 16 + (lane & 15);
                sP[(i0 + r) * PP + j] = f2bs(s[mi][fn][r]);
            }
        }
    }
    __syncthreads();

    float4v o[2][2];
    #pragma unroll
    for (int mi = 0; mi < 2; ++mi)
        #pragma unroll
        for (int nd = 0; nd < 2; ++nd) o[mi][nd] = (float4v){0.f, 0.f, 0.f, 0.f};
    #pragma unroll
    for (int jc = 0; jc < 4; ++jc) {
        short8 pf[2];
        #pragma unroll
        for (int mi = 0; mi < 2; ++mi) {
            if (wid * 2 + mi < 7) {
                int row = (wid * 2 + mi) * 16 + (lane & 15);
                pf[mi] = *reinterpret_cast<const short8*>(&sP[row * PP + jc * 32 + (lane >> 4) * 8]);
            }
        }
        #pragma unroll
        for (int nd = 0; nd < 2; ++nd) {
            short8 vf = *reinterpret_cast<const short8*>(&sVT[(nd * 16 + (lane & 15)) * VP + jc * 32 + (lane >> 4) * 8]);
            #pragma unroll
            for (int mi = 0; mi < 2; ++mi) {
                if (wid * 2 + mi < 7) o[mi][nd] = mfma16(pf[mi], vf, o[mi][nd]);
            }
        }
    }
    bf16* obase = aout + (size_t)win * Nc * 128 + head * 32;
    #pragma unroll
    for (int mi = 0; mi < 2; ++mi) {
        if (wid * 2 + mi >= 7) continue;
        #pragma unroll
        for (int nd = 0; nd < 2; ++nd) {
            int d = nd * 16 + (lane & 15);
            #pragma unroll
            for (int r = 0; r < 4; ++r) {
                int i = (wid * 2 + mi) * 16 + (lane >> 4) * 4 + r;
                if (i < 98) obase[(size_t)i * 128 + d] = __float2bfloat16(o[mi][nd][r]);
            }
        }
    }
}

extern "C" void kernel_launch(void* const* d_in, const int* in_sizes, int n_in,
                              void* d_out, int out_size, void* d_ws, size_t ws_size,
                              hipStream_t stream) {
    const float* x      = (const float*)d_in[0];
    const float* mask   = (const float*)d_in[1];
    const int*   relidx = (const int*)  d_in[2];
    const float* n1g    = (const float*)d_in[3];
    const float* n1b    = (const float*)d_in[4];
    const float* qkv_w  = (const float*)d_in[5];
    const float* qkv_b  = (const float*)d_in[6];
    const float* rpb    = (const float*)d_in[7];
    const float* proj_w = (const float*)d_in[8];
    const float* proj_b = (const float*)d_in[9];
    const float* n2g    = (const float*)d_in[10];
    const float* n2b    = (const float*)d_in[11];
    const float* fc1_w  = (const float*)d_in[12];
    const float* fc1_b  = (const float*)d_in[13];
    const float* fc2_w  = (const float*)d_in[14];
    const float* fc2_b  = (const float*)d_in[15];

    char* ws = (char*)d_ws;
    const size_t MB = 1024 * 1024;
    bf16*  xw   = (bf16*)(ws);                // [0, 24.5)    k1 -> qkvG
    bf16*  qkv  = (bf16*)(ws + 25 * MB);      // [25, 98.5)   qkvG -> attn
    bf16*  aout = (bf16*)(ws + 99 * MB);      // [99, 123.5)  attn -> proj_fused
    short* cmbT = (short*)(ws + 149 * MB);    // [149, 173.5) cmb -> attn
    bf16*  x1   = (bf16*)(ws);                // [0, 24.5)    proj_fused -> fc2 (xw dead; bf16)
    bf16*  xn2  = (bf16*)(ws + 50 * MB);      // [50, 74.5)   proj_fused -> fc1
    bf16*  h1   = (bf16*)(ws + 75 * MB);      // [75, 173)    fc1 -> fc2 (aout/cmbT dead)
    short* wbf  = (short*)(ws + 174 * MB);    // [174, 174.4) whole launch
    float* out  = (float*)d_out;

    const short* wq = wbf;
    const short* wp = wbf + 49152;
    const short* w1 = wbf + 65536;
    const short* w2 = wbf + 131072;

    k_wconv<<<768, 256, 0, stream>>>(qkv_w, proj_w, fc1_w, fc2_w, wbf);
    k_cmb<<<dim3(49, 1024), 256, 0, stream>>>(relidx, rpb, mask, cmbT);
    k_ln1_win<<<NTOK / 4, 256, 0, stream>>>(x, n1g, n1b, xw);
    k_gemm_mfma<128, 0, bf16, true><<<dim3(3, NTOK / 128), 256, 0, stream>>>((const short*)xw, wq, qkv_b, nullptr, qkv, 384);
    k_attn_mfma<<<BNc * 4, 256, 0, stream>>>(qkv, cmbT, aout);
    k_proj_fused<<<NTOK / 128, 256, 0, stream>>>((const short*)aout, wp, proj_b, x, n2g, n2b, x1, xn2);
    k_gemm_mfma<128, 2, bf16, true><<<dim3(4, NTOK / 128), 256, 0, stream>>>((const short*)xn2, w1, fc1_b, nullptr, h1, 512);
    k_gemm_mfma<512, 3, float, false><<<dim3(NTOK / 128, 1), 256, 0, stream>>>((const short*)h1, w2, fc2_b, x1, out, 128);
}

// Round 19
// 265.963 us; speedup vs baseline: 1.1841x; 1.0321x over previous
//
#include <hip/hip_runtime.h>
#include <hip/hip_bf16.h>
#include <math.h>

using bf16 = __hip_bfloat16;
typedef __attribute__((ext_vector_type(8))) short short8;
typedef __attribute__((ext_vector_type(4))) float float4v;
typedef __attribute__((ext_vector_type(4))) unsigned short ushort4v;

#define DEVI __device__ __forceinline__

constexpr int Nc = 98;
constexpr int NWIN = 256;
constexpr int BNc = 4 * NWIN;           // 1024 windows
constexpr int NTOK = 4 * 8 * 56 * 56;   // 100352 tokens

DEVI float b2f(bf16 v) { return __bfloat162float(v); }
DEVI short f2bs(float v) { bf16 h = __float2bfloat16(v); return *reinterpret_cast<short*>(&h); }

DEVI float4v mfma16(short8 a, short8 b, float4v c) {
    return __builtin_amdgcn_mfma_f32_16x16x32_bf16(a, b, c, 0, 0, 0);
}

DEVI float gelu_tanh(float x) {
    float t = 0.7978845608028654f * (x + 0.044715f * x * x * x);
    float at = fabsf(t);
    float e2 = __expf(-2.0f * at);
    float th = (1.0f - e2) / (1.0f + e2);
    th = copysignf(th, t);
    return 0.5f * x * (1.0f + th);
}

DEVI void gload16(const short* g, short* lds_base) {
    __builtin_amdgcn_global_load_lds((const __attribute__((address_space(1))) unsigned int*)g,
                                     (__attribute__((address_space(3))) unsigned int*)lds_base,
                                     16, 0, 0);
}

// ---------------- K0: merged preamble (wconv | cmb | ln1_win), independent block ranges ----------------
constexpr int PRE_WCONV = 768;              // 196608 / 256
constexpr int PRE_CMB   = 50176;            // 1024 * 12544 / 256
constexpr int PRE_LN1   = NTOK / 4;         // 25088
__global__ __launch_bounds__(256) void k_pre(const float* __restrict__ qw, const float* __restrict__ pw,
                                             const float* __restrict__ f1, const float* __restrict__ f2,
                                             short* __restrict__ wbf,
                                             const int* __restrict__ relidx, const float* __restrict__ rpb,
                                             const float* __restrict__ mask, short* __restrict__ cmbT,
                                             const float* __restrict__ x,
                                             const float* __restrict__ g1, const float* __restrict__ b1,
                                             bf16* __restrict__ xw) {
    int b = blockIdx.x, t = threadIdx.x;
    if (b < PRE_WCONV) {
        // ---- weights fp32 -> bf16 ----
        int i = b * 256 + t;
        float v;
        if (i < 49152) v = qw[i];
        else if (i < 65536) v = pw[i - 49152];
        else if (i < 131072) v = f1[i - 65536];
        else v = f2[i - 131072];
        wbf[i] = f2bs(v);
    } else if (b < PRE_WCONV + PRE_CMB) {
        // ---- combined bias+mask table, transposed ----
        int u = (b - PRE_WCONV) * 256 + t;            // [0, 1024*12544)
        int sl = u / 12544, elem = u - sl * 12544;
        int wc = sl >> 2, head = sl & 3;
        int j = elem / 112, i = elem - j * 112;
        float v;
        if (j >= 98)      v = -1e30f;
        else if (i >= 98) v = 0.f;
        else              v = rpb[relidx[i * 98 + j] * 4 + head] + mask[(size_t)wc * 9604 + i * 98 + j];
        cmbT[(size_t)sl * 12544 + elem] = f2bs(v);
    } else {
        // ---- LN1 + cyclic shift + window partition ----
        int bb2 = b - PRE_WCONV - PRE_CMB;
        int wave = (bb2 * 256 + t) >> 6;
        int lane = t & 63;
        int win = wave / Nc, n = wave % Nc;
        int bb = win >> 8;
        int rem = win & 255;
        int dblk = rem >> 6, hblk = (rem >> 3) & 7, wblk = rem & 7;
        int wd = n / 49, r49 = n % 49, wh = r49 / 7, ww = r49 % 7;
        int d = dblk * 2 + wd, h = hblk * 7 + wh, w = wblk * 7 + ww;
        int ds = d + 1;  if (ds >= 8)  ds -= 8;
        int hs = h + 3;  if (hs >= 56) hs -= 56;
        int wsp = w + 3; if (wsp >= 56) wsp -= 56;
        size_t src = ((((size_t)bb * 8 + ds) * 56 + hs) * 56 + wsp) * 128;
        int c = lane * 2;
        float2 v = *reinterpret_cast<const float2*>(x + src + c);
        float v0 = v.x, v1 = v.y;
        float s = v0 + v1, sq = v0 * v0 + v1 * v1;
        #pragma unroll
        for (int off = 32; off; off >>= 1) { s += __shfl_xor(s, off); sq += __shfl_xor(sq, off); }
        float mean = s * (1.0f / 128.0f);
        float var  = sq * (1.0f / 128.0f) - mean * mean;
        float inv  = rsqrtf(var + 1e-5f);
        size_t dst = (size_t)wave * 128 + c;
        xw[dst]     = __float2bfloat16((v0 - mean) * inv * g1[c]     + b1[c]);
        xw[dst + 1] = __float2bfloat16((v1 - mean) * inv * g1[c + 1] + b1[c + 1]);
    }
}

// ---------------- MFMA GEMM template: out = A @ W^T + bias ----------------
// EPI: 0 = qkv (scale cols<128), 2 = gelu(tanh) bf16 out, 3 = +residual(bf16) fp32 out.
// NSWAP: n-tile on blockIdx.x (fastest) so one m-tile's n-blocks are dispatch-adjacent (A L2-hot).
template<int K, int EPI, typename OutT, bool NSWAP>
__global__ __launch_bounds__(256) void k_gemm_mfma(const short* __restrict__ A,
                                                   const short* __restrict__ Bw,
                                                   const float* __restrict__ bias,
                                                   const bf16* __restrict__ res,
                                                   OutT* __restrict__ out, int Ncols) {
    __shared__ __align__(16) short smem[128 * 136];   // staging (2x8192) U bf16-epilogue (17408)
    short* sA = smem;
    short* sB = smem + 8192;
    int t = threadIdx.x;
    int lane = t & 63, wid = t >> 6;
    int wm = wid >> 1, wn = wid & 1;
    int rsub = lane >> 3;
    int csl  = lane & 7;
    int m0 = (NSWAP ? blockIdx.y : blockIdx.x) * 128;
    int n0 = (NSWAP ? blockIdx.x : blockIdx.y) * 128;
    float4v acc[4][4];
    #pragma unroll
    for (int a = 0; a < 4; ++a)
        #pragma unroll
        for (int b = 0; b < 4; ++b) acc[a][b] = (float4v){0.f, 0.f, 0.f, 0.f};

    for (int k0 = 0; k0 < K; k0 += 64) {
        #pragma unroll
        for (int v = 0; v < 4; ++v) {
            int row = (wid * 4 + v) * 8 + rsub;
            int ch = csl ^ (row & 7);
            gload16(A + (size_t)(m0 + row) * K + k0 + ch * 8, sA + (wid * 4 + v) * 512);
            gload16(Bw + (size_t)(n0 + row) * K + k0 + ch * 8, sB + (wid * 4 + v) * 512);
        }
        __syncthreads();
        #pragma unroll
        for (int kk = 0; kk < 2; ++kk) {
            int crb = kk * 4 + (lane >> 4);
            short8 af[4], bfr[4];
            #pragma unroll
            for (int mf = 0; mf < 4; ++mf) {
                int row = wm * 64 + mf * 16 + (lane & 15);
                af[mf] = *reinterpret_cast<const short8*>(&sA[row * 64 + (crb ^ (row & 7)) * 8]);
            }
            #pragma unroll
            for (int nf = 0; nf < 4; ++nf) {
                int row = wn * 64 + nf * 16 + (lane & 15);
                bfr[nf] = *reinterpret_cast<const short8*>(&sB[row * 64 + (crb ^ (row & 7)) * 8]);
            }
            #pragma unroll
            for (int mf = 0; mf < 4; ++mf)
                #pragma unroll
                for (int nf = 0; nf < 4; ++nf)
                    acc[mf][nf] = mfma16(af[mf], bfr[nf], acc[mf][nf]);
        }
        __syncthreads();
    }
    if constexpr (sizeof(OutT) == 2) {
        // ---- bf16 epilogue: acc -> LDS [128][136] -> 16B global stores ----
        #pragma unroll
        for (int nf = 0; nf < 4; ++nf) {
            int col = wn * 64 + nf * 16 + (lane & 15);
            int gcol = n0 + col;
            float bv = bias[gcol];
            #pragma unroll
            for (int mf = 0; mf < 4; ++mf) {
                #pragma unroll
                for (int r = 0; r < 4; ++r) {
                    int row = wm * 64 + mf * 16 + (lane >> 4) * 4 + r;
                    float v = acc[mf][nf][r] + bv;
                    if (EPI == 0) { if (gcol < 128) v *= 0.17677669529663689f; }
                    else if (EPI == 2) { v = gelu_tanh(v); }
                    smem[row * 136 + col] = f2bs(v);
                }
            }
        }
        __syncthreads();
        #pragma unroll
        for (int p = 0; p < 8; ++p) {
            int row = p * 16 + (t >> 4);
            int c0 = (t & 15) * 8;
            uint4 val = *reinterpret_cast<const uint4*>(&smem[row * 136 + c0]);
            *reinterpret_cast<uint4*>(out + (size_t)(m0 + row) * Ncols + n0 + c0) = val;
        }
    } else {
        // ---- fp32 epilogue (EPI==3): + bias + bf16 residual, direct stores ----
        #pragma unroll
        for (int mf = 0; mf < 4; ++mf) {
            #pragma unroll
            for (int nf = 0; nf < 4; ++nf) {
                int col = n0 + wn * 64 + nf * 16 + (lane & 15);
                float bvv = bias[col];
                #pragma unroll
                for (int r = 0; r < 4; ++r) {
                    size_t row = m0 + wm * 64 + mf * 16 + (lane >> 4) * 4 + r;
                    float v = acc[mf][nf][r] + bvv;
                    if (EPI == 3) v += b2f(res[row * 128 + col]);
                    out[row * Ncols + col] = v;
                }
            }
        }
    }
}

// ---------------- proj GEMM + window-reverse + residual + LN2 fused ----------------
__global__ __launch_bounds__(256) void k_proj_fused(const short* __restrict__ A,
                                                    const short* __restrict__ Bw,
                                                    const float* __restrict__ bias,
                                                    const float* __restrict__ x,
                                                    const float* __restrict__ g,
                                                    const float* __restrict__ bta,
                                                    bf16* __restrict__ x1,
                                                    bf16* __restrict__ xn2) {
    __shared__ __align__(16) short smem[128 * 136];
    short* sA = smem;
    short* sB = smem + 8192;
    int t = threadIdx.x;
    int lane = t & 63, wid = t >> 6;
    int wm = wid >> 1, wn = wid & 1;
    int rsub = lane >> 3, csl = lane & 7;
    int m0 = blockIdx.x * 128;
    float4v acc[4][4];
    #pragma unroll
    for (int a = 0; a < 4; ++a)
        #pragma unroll
        for (int b = 0; b < 4; ++b) acc[a][b] = (float4v){0.f, 0.f, 0.f, 0.f};

    for (int k0 = 0; k0 < 128; k0 += 64) {
        #pragma unroll
        for (int v = 0; v < 4; ++v) {
            int row = (wid * 4 + v) * 8 + rsub;
            int ch = csl ^ (row & 7);
            gload16(A + (size_t)(m0 + row) * 128 + k0 + ch * 8, sA + (wid * 4 + v) * 512);
            gload16(Bw + (size_t)row * 128 + k0 + ch * 8, sB + (wid * 4 + v) * 512);
        }
        __syncthreads();
        #pragma unroll
        for (int kk = 0; kk < 2; ++kk) {
            int crb = kk * 4 + (lane >> 4);
            short8 af[4], bfr[4];
            #pragma unroll
            for (int mf = 0; mf < 4; ++mf) {
                int row = wm * 64 + mf * 16 + (lane & 15);
                af[mf] = *reinterpret_cast<const short8*>(&sA[row * 64 + (crb ^ (row & 7)) * 8]);
            }
            #pragma unroll
            for (int nf = 0; nf < 4; ++nf) {
                int row = wn * 64 + nf * 16 + (lane & 15);
                bfr[nf] = *reinterpret_cast<const short8*>(&sB[row * 64 + (crb ^ (row & 7)) * 8]);
            }
            #pragma unroll
            for (int mf = 0; mf < 4; ++mf)
                #pragma unroll
                for (int nf = 0; nf < 4; ++nf)
                    acc[mf][nf] = mfma16(af[mf], bfr[nf], acc[mf][nf]);
        }
        __syncthreads();
    }

    int*   tokmap = (int*)smem;
    float* psum   = (float*)(smem + 256);
    float* psq    = (float*)(smem + 768);
    if (t < 128) {
        int wr2 = m0 + t;
        int win = wr2 / 98, n = wr2 - win * 98;
        int bb = win >> 8, rem = win & 255;
        int dblk = rem >> 6, hblk = (rem >> 3) & 7, wblk = rem & 7;
        int wd = n / 49, r49 = n - wd * 49, wh = r49 / 7, ww = r49 - wh * 7;
        int d = dblk * 2 + wd, h = hblk * 7 + wh, w = wblk * 7 + ww;
        int dd = d + 1;  if (dd >= 8)  dd -= 8;
        int hh = h + 3;  if (hh >= 56) hh -= 56;
        int w2 = w + 3;  if (w2 >= 56) w2 -= 56;
        tokmap[t] = ((bb * 8 + dd) * 56 + hh) * 56 + w2;
    }
    __syncthreads();

    #pragma unroll
    for (int mf = 0; mf < 4; ++mf) {
        #pragma unroll
        for (int r = 0; r < 4; ++r) {
            int row = wm * 64 + mf * 16 + (lane >> 4) * 4 + r;
            int tok = tokmap[row];
            float s = 0.f, sq = 0.f;
            #pragma unroll
            for (int nf = 0; nf < 4; ++nf) {
                int col = wn * 64 + nf * 16 + (lane & 15);
                float vv = acc[mf][nf][r] + bias[col] + x[(size_t)tok * 128 + col];
                acc[mf][nf][r] = vv;
                s += vv; sq += vv * vv;
            }
            #pragma unroll
            for (int m = 1; m <= 8; m <<= 1) { s += __shfl_xor(s, m); sq += __shfl_xor(sq, m); }
            if ((lane & 15) == 0) { psum[row * 2 + wn] = s; psq[row * 2 + wn] = sq; }
        }
    }
    __syncthreads();
    #pragma unroll
    for (int mf = 0; mf < 4; ++mf) {
        #pragma unroll
        for (int r = 0; r < 4; ++r) {
            int row = wm * 64 + mf * 16 + (lane >> 4) * 4 + r;
            int tok = tokmap[row];
            float s  = psum[row * 2] + psum[row * 2 + 1];
            float sq = psq[row * 2]  + psq[row * 2 + 1];
            float mean = s * (1.0f / 128.0f);
            float var  = sq * (1.0f / 128.0f) - mean * mean;
            float inv  = rsqrtf(var + 1e-5f);
            #pragma unroll
            for (int nf = 0; nf < 4; ++nf) {
                int col = wn * 64 + nf * 16 + (lane & 15);
                float vv = acc[mf][nf][r];
                x1[(size_t)tok * 128 + col] = __float2bfloat16(vv);
                xn2[(size_t)tok * 128 + col] = __float2bfloat16((vv - mean) * inv * g[col] + bta[col]);
            }
        }
    }
}

// ---------------- K3: MFMA window attention ----------------
__global__ __launch_bounds__(256, 4) void k_attn_mfma(const bf16* __restrict__ qkv,
                                                      const short* __restrict__ cmbT,
                                                      bf16* __restrict__ aout) {
    constexpr int QP = 40;
    constexpr int VP = 136;
    constexpr int PP = 136;
    __shared__ __align__(16) char smem[8704 + 30464];
    short* sVT = (short*)smem;
    short* sQ  = (short*)(smem + 8704);
    short* sK  = (short*)(smem + 8704 + 8960);
    short* sP  = (short*)(smem + 8704);
    int t = threadIdx.x, lane = t & 63, wid = t >> 6;
    int win = blockIdx.x >> 2, head = blockIdx.x & 3;
    const bf16* base = qkv + (size_t)win * Nc * 384 + head * 32;

    for (int idx = t; idx < Nc * 4; idx += 256) {
        int i = idx >> 2, g = idx & 3;
        uint4 q4 = *reinterpret_cast<const uint4*>(base + (size_t)i * 384 + g * 8);
        uint4 k4 = *reinterpret_cast<const uint4*>(base + (size_t)i * 384 + 128 + g * 8);
        uint4 v4 = *reinterpret_cast<const uint4*>(base + (size_t)i * 384 + 256 + g * 8);
        *reinterpret_cast<uint4*>(&sQ[i * QP + g * 8]) = q4;
        *reinterpret_cast<uint4*>(&sK[i * QP + g * 8]) = k4;
        const short* vp = reinterpret_cast<const short*>(&v4);
        #pragma unroll
        for (int e = 0; e < 8; ++e) sVT[(g * 8 + e) * VP + i] = vp[e];
    }
    for (int idx = t; idx < 14 * QP; idx += 256) {
        int r = 98 + idx / QP, c = idx % QP;
        sQ[r * QP + c] = 0; sK[r * QP + c] = 0;
    }
    for (int idx = t; idx < 32 * 30; idx += 256) {
        int d = idx / 30, c = 98 + idx % 30;
        sVT[d * VP + c] = 0;
    }
    __syncthreads();

    float4v s[2][7];
    #pragma unroll
    for (int mi = 0; mi < 2; ++mi)
        #pragma unroll
        for (int fn = 0; fn < 7; ++fn) s[mi][fn] = (float4v){0.f, 0.f, 0.f, 0.f};
    short8 qf[2];
    #pragma unroll
    for (int mi = 0; mi < 2; ++mi) {
        if (wid * 2 + mi < 7) {
            int row = (wid * 2 + mi) * 16 + (lane & 15);
            qf[mi] = *reinterpret_cast<const short8*>(&sQ[row * QP + (lane >> 4) * 8]);
        }
    }
    #pragma unroll
    for (int fn = 0; fn < 7; ++fn) {
        short8 kf = *reinterpret_cast<const short8*>(&sK[(fn * 16 + (lane & 15)) * QP + (lane >> 4) * 8]);
        #pragma unroll
        for (int mi = 0; mi < 2; ++mi) {
            if (wid * 2 + mi < 7) s[mi][fn] = mfma16(qf[mi], kf, s[mi][fn]);
        }
    }

    const unsigned short* cb = (const unsigned short*)(cmbT + (size_t)((win & 255) * 4 + head) * 12544);
    #pragma unroll
    for (int mi = 0; mi < 2; ++mi) {
        if (wid * 2 + mi >= 7) continue;
        int i0 = (wid * 2 + mi) * 16 + (lane >> 4) * 4;
        #pragma unroll
        for (int fn = 0; fn < 7; ++fn) {
            int j = fn * 16 + (lane & 15);
            ushort4v bm4 = *reinterpret_cast<const ushort4v*>(cb + j * 112 + i0);
            #pragma unroll
            for (int r = 0; r < 4; ++r) {
                union { unsigned u; float f; } cv; cv.u = ((unsigned)bm4[r]) << 16;
                s[mi][fn][r] = __expf(s[mi][fn][r] + cv.f);
            }
        }
        #pragma unroll
        for (int r = 0; r < 4; ++r) {
            float sum = 0.f;
            #pragma unroll
            for (int fn = 0; fn < 7; ++fn) sum += s[mi][fn][r];
            #pragma unroll
            for (int m = 1; m <= 8; m <<= 1) sum += __shfl_xor(sum, m);
            float inv = 1.0f / sum;
            #pragma unroll
            for (int fn = 0; fn < 7; ++fn) s[mi][fn][r] *= inv;
        }
    }
    __syncthreads();

    for (int idx = t; idx < 112 * 16; idx += 256) {
        int rr = idx >> 4, c2 = 112 + (idx & 15);
        sP[rr * PP + c2] = 0;
    }
    #pragma unroll
    for (int mi = 0; mi < 2; ++mi) {
        if (wid * 2 + mi >= 7) continue;
        int i0 = (wid * 2 + mi) * 16 + (lane >> 4) * 4;
        #pragma unroll
        for (int r = 0; r < 4; ++r) {
            #pragma unroll
            for (int fn = 0; fn < 7; ++fn) {
                int j = fn * 16 + (lane & 15);
                sP[(i0 + r) * PP + j] = f2bs(s[mi][fn][r]);
            }
        }
    }
    __syncthreads();

    float4v o[2][2];
    #pragma unroll
    for (int mi = 0; mi < 2; ++mi)
        #pragma unroll
        for (int nd = 0; nd < 2; ++nd) o[mi][nd] = (float4v){0.f, 0.f, 0.f, 0.f};
    #pragma unroll
    for (int jc = 0; jc < 4; ++jc) {
        short8 pf[2];
        #pragma unroll
        for (int mi = 0; mi < 2; ++mi) {
            if (wid * 2 + mi < 7) {
                int row = (wid * 2 + mi) * 16 + (lane & 15);
                pf[mi] = *reinterpret_cast<const short8*>(&sP[row * PP + jc * 32 + (lane >> 4) * 8]);
            }
        }
        #pragma unroll
        for (int nd = 0; nd < 2; ++nd) {
            short8 vf = *reinterpret_cast<const short8*>(&sVT[(nd * 16 + (lane & 15)) * VP + jc * 32 + (lane >> 4) * 8]);
            #pragma unroll
            for (int mi = 0; mi < 2; ++mi) {
                if (wid * 2 + mi < 7) o[mi][nd] = mfma16(pf[mi], vf, o[mi][nd]);
            }
        }
    }
    bf16* obase = aout + (size_t)win * Nc * 128 + head * 32;
    #pragma unroll
    for (int mi = 0; mi < 2; ++mi) {
        if (wid * 2 + mi >= 7) continue;
        #pragma unroll
        for (int nd = 0; nd < 2; ++nd) {
            int d = nd * 16 + (lane & 15);
            #pragma unroll
            for (int r = 0; r < 4; ++r) {
                int i = (wid * 2 + mi) * 16 + (lane >> 4) * 4 + r;
                if (i < 98) obase[(size_t)i * 128 + d] = __float2bfloat16(o[mi][nd][r]);
            }
        }
    }
}

extern "C" void kernel_launch(void* const* d_in, const int* in_sizes, int n_in,
                              void* d_out, int out_size, void* d_ws, size_t ws_size,
                              hipStream_t stream) {
    const float* x      = (const float*)d_in[0];
    const float* mask   = (const float*)d_in[1];
    const int*   relidx = (const int*)  d_in[2];
    const float* n1g    = (const float*)d_in[3];
    const float* n1b    = (const float*)d_in[4];
    const float* qkv_w  = (const float*)d_in[5];
    const float* qkv_b  = (const float*)d_in[6];
    const float* rpb    = (const float*)d_in[7];
    const float* proj_w = (const float*)d_in[8];
    const float* proj_b = (const float*)d_in[9];
    const float* n2g    = (const float*)d_in[10];
    const float* n2b    = (const float*)d_in[11];
    const float* fc1_w  = (const float*)d_in[12];
    const float* fc1_b  = (const float*)d_in[13];
    const float* fc2_w  = (const float*)d_in[14];
    const float* fc2_b  = (const float*)d_in[15];

    char* ws = (char*)d_ws;
    const size_t MB = 1024 * 1024;
    bf16*  xw   = (bf16*)(ws);                // [0, 24.5)    pre -> qkvG
    bf16*  qkv  = (bf16*)(ws + 25 * MB);      // [25, 98.5)   qkvG -> attn
    bf16*  aout = (bf16*)(ws + 99 * MB);      // [99, 123.5)  attn -> proj_fused
    short* cmbT = (short*)(ws + 149 * MB);    // [149, 173.5) pre -> attn
    bf16*  x1   = (bf16*)(ws);                // [0, 24.5)    proj_fused -> fc2 (xw dead; bf16)
    bf16*  xn2  = (bf16*)(ws + 50 * MB);      // [50, 74.5)   proj_fused -> fc1
    bf16*  h1   = (bf16*)(ws + 75 * MB);      // [75, 173)    fc1 -> fc2 (aout/cmbT dead)
    short* wbf  = (short*)(ws + 174 * MB);    // [174, 174.4) whole launch
    float* out  = (float*)d_out;

    const short* wq = wbf;
    const short* wp = wbf + 49152;
    const short* w1 = wbf + 65536;
    const short* w2 = wbf + 131072;

    k_pre<<<PRE_WCONV + PRE_CMB + PRE_LN1, 256, 0, stream>>>(qkv_w, proj_w, fc1_w, fc2_w, wbf,
                                                             relidx, rpb, mask, cmbT,
                                                             x, n1g, n1b, xw);
    k_gemm_mfma<128, 0, bf16, true><<<dim3(3, NTOK / 128), 256, 0, stream>>>((const short*)xw, wq, qkv_b, nullptr, qkv, 384);
    k_attn_mfma<<<BNc * 4, 256, 0, stream>>>(qkv, cmbT, aout);
    k_proj_fused<<<NTOK / 128, 256, 0, stream>>>((const short*)aout, wp, proj_b, x, n2g, n2b, x1, xn2);
    k_gemm_mfma<128, 2, bf16, true><<<dim3(4, NTOK / 128), 256, 0, stream>>>((const short*)xn2, w1, fc1_b, nullptr, h1, 512);
    k_gemm_mfma<512, 3, float, false><<<dim3(NTOK / 128, 1), 256, 0, stream>>>((const short*)h1, w2, fc2_b, x1, out, 128);
}

// Round 20
// 237.141 us; speedup vs baseline: 1.3280x; 1.1215x over previous
//
#include <hip/hip_runtime.h>
#include <hip/hip_bf16.h>
#include <math.h>

using bf16 = __hip_bfloat16;
typedef __attribute__((ext_vector_type(8))) short short8;
typedef __attribute__((ext_vector_type(4))) float float4v;
typedef __attribute__((ext_vector_type(4))) unsigned short ushort4v;

#define DEVI __device__ __forceinline__

constexpr int Nc = 98;
constexpr int NWIN = 256;
constexpr int BNc = 4 * NWIN;           // 1024 windows
constexpr int NTOK = 4 * 8 * 56 * 56;   // 100352 tokens

DEVI float b2f(bf16 v) { return __bfloat162float(v); }
DEVI short f2bs(float v) { bf16 h = __float2bfloat16(v); return *reinterpret_cast<short*>(&h); }
DEVI float us2f(unsigned short u) { union { unsigned u32; float f; } c; c.u32 = ((unsigned)u) << 16; return c.f; }

DEVI float4v mfma16(short8 a, short8 b, float4v c) {
    return __builtin_amdgcn_mfma_f32_16x16x32_bf16(a, b, c, 0, 0, 0);
}

DEVI float gelu_tanh(float x) {
    float t = 0.7978845608028654f * (x + 0.044715f * x * x * x);
    float at = fabsf(t);
    float e2 = __expf(-2.0f * at);
    float th = (1.0f - e2) / (1.0f + e2);
    th = copysignf(th, t);
    return 0.5f * x * (1.0f + th);
}

DEVI void gload16(const short* g, short* lds_base) {
    __builtin_amdgcn_global_load_lds((const __attribute__((address_space(1))) unsigned int*)g,
                                     (__attribute__((address_space(3))) unsigned int*)lds_base,
                                     16, 0, 0);
}

// ---------------- K0: merged preamble (wconv | biasT | maskT | ln1_win) ----------------
constexpr int PRE_WCONV = 768;              // 196608 / 256
constexpr int PRE_BIAST = 196;              // 4 * 12544 / 256
constexpr int PRE_MASKT = 12544;            // 256 * 12544 / 256
constexpr int PRE_LN1   = NTOK / 4;         // 25088
__global__ __launch_bounds__(256) void k_pre(const float* __restrict__ qw, const float* __restrict__ pw,
                                             const float* __restrict__ f1, const float* __restrict__ f2,
                                             short* __restrict__ wbf,
                                             const int* __restrict__ relidx, const float* __restrict__ rpb,
                                             const float* __restrict__ mask,
                                             short* __restrict__ biasT, short* __restrict__ maskT,
                                             const float* __restrict__ x,
                                             const float* __restrict__ g1, const float* __restrict__ b1,
                                             bf16* __restrict__ xw) {
    int b = blockIdx.x, t = threadIdx.x;
    if (b < PRE_WCONV) {
        // ---- weights fp32 -> bf16 ----
        int i = b * 256 + t;
        float v;
        if (i < 49152) v = qw[i];
        else if (i < 65536) v = pw[i - 49152];
        else if (i < 131072) v = f1[i - 65536];
        else v = f2[i - 131072];
        wbf[i] = f2bs(v);
    } else if (b < PRE_WCONV + PRE_BIAST) {
        // ---- biasT[h][j*112+i] = rpb-bias transposed; -1e30 for j-pad, 0 for i-pad ----
        int u = (b - PRE_WCONV) * 256 + t;            // [0, 50176)
        int h = u / 12544, elem = u - h * 12544;
        int j = elem / 112, i = elem - j * 112;
        float v;
        if (j >= 98)      v = -1e30f;
        else if (i >= 98) v = 0.f;
        else              v = rpb[relidx[i * 98 + j] * 4 + h];
        biasT[(size_t)h * 12544 + elem] = f2bs(v);
    } else if (b < PRE_WCONV + PRE_BIAST + PRE_MASKT) {
        // ---- maskT[wc][j*112+i] = mask[wc][i][j]; 0 in pads ----
        int u = (b - PRE_WCONV - PRE_BIAST) * 256 + t;  // [0, 3211264)
        int wc = u / 12544, elem = u - wc * 12544;
        int j = elem / 112, i = elem - j * 112;
        float v = (j < 98 && i < 98) ? mask[(size_t)wc * 9604 + i * 98 + j] : 0.f;
        maskT[(size_t)wc * 12544 + elem] = f2bs(v);
    } else {
        // ---- LN1 + cyclic shift + window partition ----
        int bb2 = b - PRE_WCONV - PRE_BIAST - PRE_MASKT;
        int wave = (bb2 * 256 + t) >> 6;
        int lane = t & 63;
        int win = wave / Nc, n = wave % Nc;
        int bb = win >> 8;
        int rem = win & 255;
        int dblk = rem >> 6, hblk = (rem >> 3) & 7, wblk = rem & 7;
        int wd = n / 49, r49 = n % 49, wh = r49 / 7, ww = r49 % 7;
        int d = dblk * 2 + wd, h = hblk * 7 + wh, w = wblk * 7 + ww;
        int ds = d + 1;  if (ds >= 8)  ds -= 8;
        int hs = h + 3;  if (hs >= 56) hs -= 56;
        int wsp = w + 3; if (wsp >= 56) wsp -= 56;
        size_t src = ((((size_t)bb * 8 + ds) * 56 + hs) * 56 + wsp) * 128;
        int c = lane * 2;
        float2 v = *reinterpret_cast<const float2*>(x + src + c);
        float v0 = v.x, v1 = v.y;
        float s = v0 + v1, sq = v0 * v0 + v1 * v1;
        #pragma unroll
        for (int off = 32; off; off >>= 1) { s += __shfl_xor(s, off); sq += __shfl_xor(sq, off); }
        float mean = s * (1.0f / 128.0f);
        float var  = sq * (1.0f / 128.0f) - mean * mean;
        float inv  = rsqrtf(var + 1e-5f);
        size_t dst = (size_t)wave * 128 + c;
        xw[dst]     = __float2bfloat16((v0 - mean) * inv * g1[c]     + b1[c]);
        xw[dst + 1] = __float2bfloat16((v1 - mean) * inv * g1[c + 1] + b1[c + 1]);
    }
}

// ---------------- MFMA GEMM template: out = A @ W^T + bias ----------------
// EPI: 0 = qkv (scale cols<128), 2 = gelu(tanh) bf16 out, 3 = +residual(bf16) fp32 out.
// NSWAP: n-tile on blockIdx.x (fastest) so one m-tile's n-blocks are dispatch-adjacent (A L2-hot).
template<int K, int EPI, typename OutT, bool NSWAP>
__global__ __launch_bounds__(256) void k_gemm_mfma(const short* __restrict__ A,
                                                   const short* __restrict__ Bw,
                                                   const float* __restrict__ bias,
                                                   const bf16* __restrict__ res,
                                                   OutT* __restrict__ out, int Ncols) {
    __shared__ __align__(16) short smem[128 * 136];   // staging (2x8192) U bf16-epilogue (17408)
    short* sA = smem;
    short* sB = smem + 8192;
    int t = threadIdx.x;
    int lane = t & 63, wid = t >> 6;
    int wm = wid >> 1, wn = wid & 1;
    int rsub = lane >> 3;
    int csl  = lane & 7;
    int m0 = (NSWAP ? blockIdx.y : blockIdx.x) * 128;
    int n0 = (NSWAP ? blockIdx.x : blockIdx.y) * 128;
    float4v acc[4][4];
    #pragma unroll
    for (int a = 0; a < 4; ++a)
        #pragma unroll
        for (int b = 0; b < 4; ++b) acc[a][b] = (float4v){0.f, 0.f, 0.f, 0.f};

    for (int k0 = 0; k0 < K; k0 += 64) {
        #pragma unroll
        for (int v = 0; v < 4; ++v) {
            int row = (wid * 4 + v) * 8 + rsub;
            int ch = csl ^ (row & 7);
            gload16(A + (size_t)(m0 + row) * K + k0 + ch * 8, sA + (wid * 4 + v) * 512);
            gload16(Bw + (size_t)(n0 + row) * K + k0 + ch * 8, sB + (wid * 4 + v) * 512);
        }
        __syncthreads();
        #pragma unroll
        for (int kk = 0; kk < 2; ++kk) {
            int crb = kk * 4 + (lane >> 4);
            short8 af[4], bfr[4];
            #pragma unroll
            for (int mf = 0; mf < 4; ++mf) {
                int row = wm * 64 + mf * 16 + (lane & 15);
                af[mf] = *reinterpret_cast<const short8*>(&sA[row * 64 + (crb ^ (row & 7)) * 8]);
            }
            #pragma unroll
            for (int nf = 0; nf < 4; ++nf) {
                int row = wn * 64 + nf * 16 + (lane & 15);
                bfr[nf] = *reinterpret_cast<const short8*>(&sB[row * 64 + (crb ^ (row & 7)) * 8]);
            }
            #pragma unroll
            for (int mf = 0; mf < 4; ++mf)
                #pragma unroll
                for (int nf = 0; nf < 4; ++nf)
                    acc[mf][nf] = mfma16(af[mf], bfr[nf], acc[mf][nf]);
        }
        __syncthreads();
    }
    if constexpr (sizeof(OutT) == 2) {
        // ---- bf16 epilogue: acc -> LDS [128][136] -> 16B global stores ----
        #pragma unroll
        for (int nf = 0; nf < 4; ++nf) {
            int col = wn * 64 + nf * 16 + (lane & 15);
            int gcol = n0 + col;
            float bv = bias[gcol];
            #pragma unroll
            for (int mf = 0; mf < 4; ++mf) {
                #pragma unroll
                for (int r = 0; r < 4; ++r) {
                    int row = wm * 64 + mf * 16 + (lane >> 4) * 4 + r;
                    float v = acc[mf][nf][r] + bv;
                    if (EPI == 0) { if (gcol < 128) v *= 0.17677669529663689f; }
                    else if (EPI == 2) { v = gelu_tanh(v); }
                    smem[row * 136 + col] = f2bs(v);
                }
            }
        }
        __syncthreads();
        #pragma unroll
        for (int p = 0; p < 8; ++p) {
            int row = p * 16 + (t >> 4);
            int c0 = (t & 15) * 8;
            uint4 val = *reinterpret_cast<const uint4*>(&smem[row * 136 + c0]);
            *reinterpret_cast<uint4*>(out + (size_t)(m0 + row) * Ncols + n0 + c0) = val;
        }
    } else {
        // ---- fp32 epilogue (EPI==3): + bias + bf16 residual, direct stores ----
        #pragma unroll
        for (int mf = 0; mf < 4; ++mf) {
            #pragma unroll
            for (int nf = 0; nf < 4; ++nf) {
                int col = n0 + wn * 64 + nf * 16 + (lane & 15);
                float bvv = bias[col];
                #pragma unroll
                for (int r = 0; r < 4; ++r) {
                    size_t row = m0 + wm * 64 + mf * 16 + (lane >> 4) * 4 + r;
                    float v = acc[mf][nf][r] + bvv;
                    if (EPI == 3) v += b2f(res[row * 128 + col]);
                    out[row * Ncols + col] = v;
                }
            }
        }
    }
}

// ---------------- proj GEMM + window-reverse + residual + LN2 fused ----------------
__global__ __launch_bounds__(256) void k_proj_fused(const short* __restrict__ A,
                                                    const short* __restrict__ Bw,
                                                    const float* __restrict__ bias,
                                                    const float* __restrict__ x,
                                                    const float* __restrict__ g,
                                                    const float* __restrict__ bta,
                                                    bf16* __restrict__ x1,
                                                    bf16* __restrict__ xn2) {
    __shared__ __align__(16) short smem[128 * 136];
    short* sA = smem;
    short* sB = smem + 8192;
    int t = threadIdx.x;
    int lane = t & 63, wid = t >> 6;
    int wm = wid >> 1, wn = wid & 1;
    int rsub = lane >> 3, csl = lane & 7;
    int m0 = blockIdx.x * 128;
    float4v acc[4][4];
    #pragma unroll
    for (int a = 0; a < 4; ++a)
        #pragma unroll
        for (int b = 0; b < 4; ++b) acc[a][b] = (float4v){0.f, 0.f, 0.f, 0.f};

    for (int k0 = 0; k0 < 128; k0 += 64) {
        #pragma unroll
        for (int v = 0; v < 4; ++v) {
            int row = (wid * 4 + v) * 8 + rsub;
            int ch = csl ^ (row & 7);
            gload16(A + (size_t)(m0 + row) * 128 + k0 + ch * 8, sA + (wid * 4 + v) * 512);
            gload16(Bw + (size_t)row * 128 + k0 + ch * 8, sB + (wid * 4 + v) * 512);
        }
        __syncthreads();
        #pragma unroll
        for (int kk = 0; kk < 2; ++kk) {
            int crb = kk * 4 + (lane >> 4);
            short8 af[4], bfr[4];
            #pragma unroll
            for (int mf = 0; mf < 4; ++mf) {
                int row = wm * 64 + mf * 16 + (lane & 15);
                af[mf] = *reinterpret_cast<const short8*>(&sA[row * 64 + (crb ^ (row & 7)) * 8]);
            }
            #pragma unroll
            for (int nf = 0; nf < 4; ++nf) {
                int row = wn * 64 + nf * 16 + (lane & 15);
                bfr[nf] = *reinterpret_cast<const short8*>(&sB[row * 64 + (crb ^ (row & 7)) * 8]);
            }
            #pragma unroll
            for (int mf = 0; mf < 4; ++mf)
                #pragma unroll
                for (int nf = 0; nf < 4; ++nf)
                    acc[mf][nf] = mfma16(af[mf], bfr[nf], acc[mf][nf]);
        }
        __syncthreads();
    }

    int*   tokmap = (int*)smem;
    float* psum   = (float*)(smem + 256);
    float* psq    = (float*)(smem + 768);
    if (t < 128) {
        int wr2 = m0 + t;
        int win = wr2 / 98, n = wr2 - win * 98;
        int bb = win >> 8, rem = win & 255;
        int dblk = rem >> 6, hblk = (rem >> 3) & 7, wblk = rem & 7;
        int wd = n / 49, r49 = n - wd * 49, wh = r49 / 7, ww = r49 - wh * 7;
        int d = dblk * 2 + wd, h = hblk * 7 + wh, w = wblk * 7 + ww;
        int dd = d + 1;  if (dd >= 8)  dd -= 8;
        int hh = h + 3;  if (hh >= 56) hh -= 56;
        int w2 = w + 3;  if (w2 >= 56) w2 -= 56;
        tokmap[t] = ((bb * 8 + dd) * 56 + hh) * 56 + w2;
    }
    __syncthreads();

    #pragma unroll
    for (int mf = 0; mf < 4; ++mf) {
        #pragma unroll
        for (int r = 0; r < 4; ++r) {
            int row = wm * 64 + mf * 16 + (lane >> 4) * 4 + r;
            int tok = tokmap[row];
            float s = 0.f, sq = 0.f;
            #pragma unroll
            for (int nf = 0; nf < 4; ++nf) {
                int col = wn * 64 + nf * 16 + (lane & 15);
                float vv = acc[mf][nf][r] + bias[col] + x[(size_t)tok * 128 + col];
                acc[mf][nf][r] = vv;
                s += vv; sq += vv * vv;
            }
            #pragma unroll
            for (int m = 1; m <= 8; m <<= 1) { s += __shfl_xor(s, m); sq += __shfl_xor(sq, m); }
            if ((lane & 15) == 0) { psum[row * 2 + wn] = s; psq[row * 2 + wn] = sq; }
        }
    }
    __syncthreads();
    #pragma unroll
    for (int mf = 0; mf < 4; ++mf) {
        #pragma unroll
        for (int r = 0; r < 4; ++r) {
            int row = wm * 64 + mf * 16 + (lane >> 4) * 4 + r;
            int tok = tokmap[row];
            float s  = psum[row * 2] + psum[row * 2 + 1];
            float sq = psq[row * 2]  + psq[row * 2 + 1];
            float mean = s * (1.0f / 128.0f);
            float var  = sq * (1.0f / 128.0f) - mean * mean;
            float inv  = rsqrtf(var + 1e-5f);
            #pragma unroll
            for (int nf = 0; nf < 4; ++nf) {
                int col = wn * 64 + nf * 16 + (lane & 15);
                float vv = acc[mf][nf][r];
                x1[(size_t)tok * 128 + col] = __float2bfloat16(vv);
                xn2[(size_t)tok * 128 + col] = __float2bfloat16((vv - mean) * inv * g[col] + bta[col]);
            }
        }
    }
}

// ---------------- K3: MFMA window attention (biasT + maskT added on the fly) ----------------
__global__ __launch_bounds__(256, 4) void k_attn_mfma(const bf16* __restrict__ qkv,
                                                      const short* __restrict__ biasT,
                                                      const short* __restrict__ maskT,
                                                      bf16* __restrict__ aout) {
    constexpr int QP = 40;
    constexpr int VP = 136;
    constexpr int PP = 136;
    __shared__ __align__(16) char smem[8704 + 30464];
    short* sVT = (short*)smem;
    short* sQ  = (short*)(smem + 8704);
    short* sK  = (short*)(smem + 8704 + 8960);
    short* sP  = (short*)(smem + 8704);
    int t = threadIdx.x, lane = t & 63, wid = t >> 6;
    int win = blockIdx.x >> 2, head = blockIdx.x & 3;
    const bf16* base = qkv + (size_t)win * Nc * 384 + head * 32;

    for (int idx = t; idx < Nc * 4; idx += 256) {
        int i = idx >> 2, g = idx & 3;
        uint4 q4 = *reinterpret_cast<const uint4*>(base + (size_t)i * 384 + g * 8);
        uint4 k4 = *reinterpret_cast<const uint4*>(base + (size_t)i * 384 + 128 + g * 8);
        uint4 v4 = *reinterpret_cast<const uint4*>(base + (size_t)i * 384 + 256 + g * 8);
        *reinterpret_cast<uint4*>(&sQ[i * QP + g * 8]) = q4;
        *reinterpret_cast<uint4*>(&sK[i * QP + g * 8]) = k4;
        const short* vp = reinterpret_cast<const short*>(&v4);
        #pragma unroll
        for (int e = 0; e < 8; ++e) sVT[(g * 8 + e) * VP + i] = vp[e];
    }
    for (int idx = t; idx < 14 * QP; idx += 256) {
        int r = 98 + idx / QP, c = idx % QP;
        sQ[r * QP + c] = 0; sK[r * QP + c] = 0;
    }
    for (int idx = t; idx < 32 * 30; idx += 256) {
        int d = idx / 30, c = 98 + idx % 30;
        sVT[d * VP + c] = 0;
    }
    __syncthreads();

    float4v s[2][7];
    #pragma unroll
    for (int mi = 0; mi < 2; ++mi)
        #pragma unroll
        for (int fn = 0; fn < 7; ++fn) s[mi][fn] = (float4v){0.f, 0.f, 0.f, 0.f};
    short8 qf[2];
    #pragma unroll
    for (int mi = 0; mi < 2; ++mi) {
        if (wid * 2 + mi < 7) {
            int row = (wid * 2 + mi) * 16 + (lane & 15);
            qf[mi] = *reinterpret_cast<const short8*>(&sQ[row * QP + (lane >> 4) * 8]);
        }
    }
    #pragma unroll
    for (int fn = 0; fn < 7; ++fn) {
        short8 kf = *reinterpret_cast<const short8*>(&sK[(fn * 16 + (lane & 15)) * QP + (lane >> 4) * 8]);
        #pragma unroll
        for (int mi = 0; mi < 2; ++mi) {
            if (wid * 2 + mi < 7) s[mi][fn] = mfma16(qf[mi], kf, s[mi][fn]);
        }
    }

    const unsigned short* bT = (const unsigned short*)(biasT + (size_t)head * 12544);
    const unsigned short* mT = (const unsigned short*)(maskT + (size_t)(win & 255) * 12544);
    #pragma unroll
    for (int mi = 0; mi < 2; ++mi) {
        if (wid * 2 + mi >= 7) continue;
        int i0 = (wid * 2 + mi) * 16 + (lane >> 4) * 4;
        #pragma unroll
        for (int fn = 0; fn < 7; ++fn) {
            int j = fn * 16 + (lane & 15);
            ushort4v b4 = *reinterpret_cast<const ushort4v*>(bT + j * 112 + i0);
            ushort4v m4 = *reinterpret_cast<const ushort4v*>(mT + j * 112 + i0);
            #pragma unroll
            for (int r = 0; r < 4; ++r) {
                s[mi][fn][r] = __expf(s[mi][fn][r] + us2f(b4[r]) + us2f(m4[r]));
            }
        }
        #pragma unroll
        for (int r = 0; r < 4; ++r) {
            float sum = 0.f;
            #pragma unroll
            for (int fn = 0; fn < 7; ++fn) sum += s[mi][fn][r];
            #pragma unroll
            for (int m = 1; m <= 8; m <<= 1) sum += __shfl_xor(sum, m);
            float inv = 1.0f / sum;
            #pragma unroll
            for (int fn = 0; fn < 7; ++fn) s[mi][fn][r] *= inv;
        }
    }
    __syncthreads();

    for (int idx = t; idx < 112 * 16; idx += 256) {
        int rr = idx >> 4, c2 = 112 + (idx & 15);
        sP[rr * PP + c2] = 0;
    }
    #pragma unroll
    for (int mi = 0; mi < 2; ++mi) {
        if (wid * 2 + mi >= 7) continue;
        int i0 = (wid * 2 + mi) * 16 + (lane >> 4) * 4;
        #pragma unroll
        for (int r = 0; r < 4; ++r) {
            #pragma unroll
            for (int fn = 0; fn < 7; ++fn) {
                int j = fn * 16 + (lane & 15);
                sP[(i0 + r) * PP + j] = f2bs(s[mi][fn][r]);
            }
        }
    }
    __syncthreads();

    float4v o[2][2];
    #pragma unroll
    for (int mi = 0; mi < 2; ++mi)
        #pragma unroll
        for (int nd = 0; nd < 2; ++nd) o[mi][nd] = (float4v){0.f, 0.f, 0.f, 0.f};
    #pragma unroll
    for (int jc = 0; jc < 4; ++jc) {
        short8 pf[2];
        #pragma unroll
        for (int mi = 0; mi < 2; ++mi) {
            if (wid * 2 + mi < 7) {
                int row = (wid * 2 + mi) * 16 + (lane & 15);
                pf[mi] = *reinterpret_cast<const short8*>(&sP[row * PP + jc * 32 + (lane >> 4) * 8]);
            }
        }
        #pragma unroll
        for (int nd = 0; nd < 2; ++nd) {
            short8 vf = *reinterpret_cast<const short8*>(&sVT[(nd * 16 + (lane & 15)) * VP + jc * 32 + (lane >> 4) * 8]);
            #pragma unroll
            for (int mi = 0; mi < 2; ++mi) {
                if (wid * 2 + mi < 7) o[mi][nd] = mfma16(pf[mi], vf, o[mi][nd]);
            }
        }
    }
    bf16* obase = aout + (size_t)win * Nc * 128 + head * 32;
    #pragma unroll
    for (int mi = 0; mi < 2; ++mi) {
        if (wid * 2 + mi >= 7) continue;
        #pragma unroll
        for (int nd = 0; nd < 2; ++nd) {
            int d = nd * 16 + (lane & 15);
            #pragma unroll
            for (int r = 0; r < 4; ++r) {
                int i = (wid * 2 + mi) * 16 + (lane >> 4) * 4 + r;
                if (i < 98) obase[(size_t)i * 128 + d] = __float2bfloat16(o[mi][nd][r]);
            }
        }
    }
}

extern "C" void kernel_launch(void* const* d_in, const int* in_sizes, int n_in,
                              void* d_out, int out_size, void* d_ws, size_t ws_size,
                              hipStream_t stream) {
    const float* x      = (const float*)d_in[0];
    const float* mask   = (const float*)d_in[1];
    const int*   relidx = (const int*)  d_in[2];
    const float* n1g    = (const float*)d_in[3];
    const float* n1b    = (const float*)d_in[4];
    const float* qkv_w  = (const float*)d_in[5];
    const float* qkv_b  = (const float*)d_in[6];
    const float* rpb    = (const float*)d_in[7];
    const float* proj_w = (const float*)d_in[8];
    const float* proj_b = (const float*)d_in[9];
    const float* n2g    = (const float*)d_in[10];
    const float* n2b    = (const float*)d_in[11];
    const float* fc1_w  = (const float*)d_in[12];
    const float* fc1_b  = (const float*)d_in[13];
    const float* fc2_w  = (const float*)d_in[14];
    const float* fc2_b  = (const float*)d_in[15];

    char* ws = (char*)d_ws;
    const size_t MB = 1024 * 1024;
    bf16*  xw    = (bf16*)(ws);                // [0, 24.5)    pre -> qkvG
    bf16*  qkv   = (bf16*)(ws + 25 * MB);      // [25, 98.5)   qkvG -> attn
    bf16*  aout  = (bf16*)(ws + 99 * MB);      // [99, 123.5)  attn -> proj_fused
    short* maskT = (short*)(ws + 149 * MB);    // [149, 155.2) pre -> attn (h1 overlap OK: fc1 after attn)
    short* biasT = (short*)(ws + 156 * MB);    // [156, 156.1) pre -> attn
    bf16*  x1    = (bf16*)(ws);                // [0, 24.5)    proj_fused -> fc2 (xw dead; bf16)
    bf16*  xn2   = (bf16*)(ws + 50 * MB);      // [50, 74.5)   proj_fused -> fc1
    bf16*  h1    = (bf16*)(ws + 75 * MB);      // [75, 173)    fc1 -> fc2 (aout/maskT/biasT dead)
    short* wbf   = (short*)(ws + 174 * MB);    // [174, 174.4) whole launch
    float* out   = (float*)d_out;

    const short* wq = wbf;
    const short* wp = wbf + 49152;
    const short* w1 = wbf + 65536;
    const short* w2 = wbf + 131072;

    k_pre<<<PRE_WCONV + PRE_BIAST + PRE_MASKT + PRE_LN1, 256, 0, stream>>>(
        qkv_w, proj_w, fc1_w, fc2_w, wbf,
        relidx, rpb, mask, biasT, maskT,
        x, n1g, n1b, xw);
    k_gemm_mfma<128, 0, bf16, true><<<dim3(3, NTOK / 128), 256, 0, stream>>>((const short*)xw, wq, qkv_b, nullptr, qkv, 384);
    k_attn_mfma<<<BNc * 4, 256, 0, stream>>>(qkv, biasT, maskT, aout);
    k_proj_fused<<<NTOK / 128, 256, 0, stream>>>((const short*)aout, wp, proj_b, x, n2g, n2b, x1, xn2);
    k_gemm_mfma<128, 2, bf16, true><<<dim3(4, NTOK / 128), 256, 0, stream>>>((const short*)xn2, w1, fc1_b, nullptr, h1, 512);
    k_gemm_mfma<512, 3, float, false><<<dim3(NTOK / 128, 1), 256, 0, stream>>>((const short*)h1, w2, fc2_b, x1, out, 128);
}

// Round 21
// 226.725 us; speedup vs baseline: 1.3890x; 1.0459x over previous
//
#include <hip/hip_runtime.h>
#include <hip/hip_bf16.h>
#include <math.h>

using bf16 = __hip_bfloat16;
typedef __attribute__((ext_vector_type(8))) short short8;
typedef __attribute__((ext_vector_type(4))) float float4v;
typedef __attribute__((ext_vector_type(4))) unsigned short ushort4v;

#define DEVI __device__ __forceinline__

constexpr int Nc = 98;
constexpr int NWIN = 256;
constexpr int BNc = 4 * NWIN;           // 1024 windows
constexpr int NTOK = 4 * 8 * 56 * 56;   // 100352 tokens

DEVI float b2f(bf16 v) { return __bfloat162float(v); }
DEVI short f2bs(float v) { bf16 h = __float2bfloat16(v); return *reinterpret_cast<short*>(&h); }
DEVI float us2f(unsigned short u) { union { unsigned u32; float f; } c; c.u32 = ((unsigned)u) << 16; return c.f; }

DEVI float4v mfma16(short8 a, short8 b, float4v c) {
    return __builtin_amdgcn_mfma_f32_16x16x32_bf16(a, b, c, 0, 0, 0);
}

DEVI float gelu_tanh(float x) {
    float t = 0.7978845608028654f * (x + 0.044715f * x * x * x);
    float at = fabsf(t);
    float e2 = __expf(-2.0f * at);
    float th = (1.0f - e2) / (1.0f + e2);
    th = copysignf(th, t);
    return 0.5f * x * (1.0f + th);
}

DEVI void gload16(const short* g, short* lds_base) {
    __builtin_amdgcn_global_load_lds((const __attribute__((address_space(1))) unsigned int*)g,
                                     (__attribute__((address_space(3))) unsigned int*)lds_base,
                                     16, 0, 0);
}

// ---------------- K0: merged preamble (wconv | biasT | maskT-transpose | ln1_win) ----------------
constexpr int PRE_WCONV = 768;              // 196608 / 256
constexpr int PRE_BIAST = 196;              // 4 * 12544 / 256
constexpr int PRE_MASKT = 256;              // one block per wc slice (LDS transpose)
constexpr int PRE_LN1   = NTOK / 4;         // 25088
__global__ __launch_bounds__(256) void k_pre(const float* __restrict__ qw, const float* __restrict__ pw,
                                             const float* __restrict__ f1, const float* __restrict__ f2,
                                             short* __restrict__ wbf,
                                             const int* __restrict__ relidx, const float* __restrict__ rpb,
                                             const float* __restrict__ mask,
                                             short* __restrict__ biasT, short* __restrict__ maskT,
                                             const float* __restrict__ x,
                                             const float* __restrict__ g1, const float* __restrict__ b1,
                                             bf16* __restrict__ xw) {
    __shared__ short sM[98 * 114];                    // 22.3KB; used only by maskT blocks
    int b = blockIdx.x, t = threadIdx.x;
    if (b < PRE_WCONV) {
        // ---- weights fp32 -> bf16 ----
        int i = b * 256 + t;
        float v;
        if (i < 49152) v = qw[i];
        else if (i < 65536) v = pw[i - 49152];
        else if (i < 131072) v = f1[i - 65536];
        else v = f2[i - 131072];
        wbf[i] = f2bs(v);
    } else if (b < PRE_WCONV + PRE_BIAST) {
        // ---- biasT[h][j*112+i] = rpb-bias transposed; -1e30 for j-pad, 0 for i-pad ----
        int u = (b - PRE_WCONV) * 256 + t;            // [0, 50176)
        int h = u / 12544, elem = u - h * 12544;
        int j = elem / 112, i = elem - j * 112;
        float v;
        if (j >= 98)      v = -1e30f;
        else if (i >= 98) v = 0.f;
        else              v = rpb[relidx[i * 98 + j] * 4 + h];
        biasT[(size_t)h * 12544 + elem] = f2bs(v);
    } else if (b < PRE_WCONV + PRE_BIAST + PRE_MASKT) {
        // ---- maskT[wc][j*112+i] = mask[wc][i][j], via LDS transpose (coalesced both sides) ----
        int wc = b - PRE_WCONV - PRE_BIAST;
        for (int idx = t; idx < 98 * 98; idx += 256) {
            int i = idx / 98, j = idx - i * 98;       // j fastest -> coalesced global read
            sM[i * 114 + j] = f2bs(mask[(size_t)wc * 9604 + idx]);
        }
        __syncthreads();
        for (int odx = t; odx < 12544; odx += 256) {
            int j = odx / 112, i = odx - j * 112;     // i fastest -> coalesced global write
            short v = (j < 98 && i < 98) ? sM[i * 114 + j] : (short)0;
            maskT[(size_t)wc * 12544 + odx] = v;
        }
    } else {
        // ---- LN1 + cyclic shift + window partition ----
        int bb2 = b - PRE_WCONV - PRE_BIAST - PRE_MASKT;
        int wave = (bb2 * 256 + t) >> 6;
        int lane = t & 63;
        int win = wave / Nc, n = wave % Nc;
        int bb = win >> 8;
        int rem = win & 255;
        int dblk = rem >> 6, hblk = (rem >> 3) & 7, wblk = rem & 7;
        int wd = n / 49, r49 = n % 49, wh = r49 / 7, ww = r49 % 7;
        int d = dblk * 2 + wd, h = hblk * 7 + wh, w = wblk * 7 + ww;
        int ds = d + 1;  if (ds >= 8)  ds -= 8;
        int hs = h + 3;  if (hs >= 56) hs -= 56;
        int wsp = w + 3; if (wsp >= 56) wsp -= 56;
        size_t src = ((((size_t)bb * 8 + ds) * 56 + hs) * 56 + wsp) * 128;
        int c = lane * 2;
        float2 v = *reinterpret_cast<const float2*>(x + src + c);
        float v0 = v.x, v1 = v.y;
        float s = v0 + v1, sq = v0 * v0 + v1 * v1;
        #pragma unroll
        for (int off = 32; off; off >>= 1) { s += __shfl_xor(s, off); sq += __shfl_xor(sq, off); }
        float mean = s * (1.0f / 128.0f);
        float var  = sq * (1.0f / 128.0f) - mean * mean;
        float inv  = rsqrtf(var + 1e-5f);
        size_t dst = (size_t)wave * 128 + c;
        xw[dst]     = __float2bfloat16((v0 - mean) * inv * g1[c]     + b1[c]);
        xw[dst + 1] = __float2bfloat16((v1 - mean) * inv * g1[c + 1] + b1[c + 1]);
    }
}

// ---------------- MFMA GEMM template: out = A @ W^T + bias ----------------
// EPI: 0 = qkv (scale cols<128), 2 = gelu(tanh) bf16 out, 3 = +residual(bf16) fp32 out.
// NSWAP: n-tile on blockIdx.x (fastest) so one m-tile's n-blocks are dispatch-adjacent (A L2-hot).
template<int K, int EPI, typename OutT, bool NSWAP>
__global__ __launch_bounds__(256) void k_gemm_mfma(const short* __restrict__ A,
                                                   const short* __restrict__ Bw,
                                                   const float* __restrict__ bias,
                                                   const bf16* __restrict__ res,
                                                   OutT* __restrict__ out, int Ncols) {
    __shared__ __align__(16) short smem[128 * 136];   // staging (2x8192) U bf16-epilogue (17408)
    short* sA = smem;
    short* sB = smem + 8192;
    int t = threadIdx.x;
    int lane = t & 63, wid = t >> 6;
    int wm = wid >> 1, wn = wid & 1;
    int rsub = lane >> 3;
    int csl  = lane & 7;
    int m0 = (NSWAP ? blockIdx.y : blockIdx.x) * 128;
    int n0 = (NSWAP ? blockIdx.x : blockIdx.y) * 128;
    float4v acc[4][4];
    #pragma unroll
    for (int a = 0; a < 4; ++a)
        #pragma unroll
        for (int b = 0; b < 4; ++b) acc[a][b] = (float4v){0.f, 0.f, 0.f, 0.f};

    for (int k0 = 0; k0 < K; k0 += 64) {
        #pragma unroll
        for (int v = 0; v < 4; ++v) {
            int row = (wid * 4 + v) * 8 + rsub;
            int ch = csl ^ (row & 7);
            gload16(A + (size_t)(m0 + row) * K + k0 + ch * 8, sA + (wid * 4 + v) * 512);
            gload16(Bw + (size_t)(n0 + row) * K + k0 + ch * 8, sB + (wid * 4 + v) * 512);
        }
        __syncthreads();
        #pragma unroll
        for (int kk = 0; kk < 2; ++kk) {
            int crb = kk * 4 + (lane >> 4);
            short8 af[4], bfr[4];
            #pragma unroll
            for (int mf = 0; mf < 4; ++mf) {
                int row = wm * 64 + mf * 16 + (lane & 15);
                af[mf] = *reinterpret_cast<const short8*>(&sA[row * 64 + (crb ^ (row & 7)) * 8]);
            }
            #pragma unroll
            for (int nf = 0; nf < 4; ++nf) {
                int row = wn * 64 + nf * 16 + (lane & 15);
                bfr[nf] = *reinterpret_cast<const short8*>(&sB[row * 64 + (crb ^ (row & 7)) * 8]);
            }
            #pragma unroll
            for (int mf = 0; mf < 4; ++mf)
                #pragma unroll
                for (int nf = 0; nf < 4; ++nf)
                    acc[mf][nf] = mfma16(af[mf], bfr[nf], acc[mf][nf]);
        }
        __syncthreads();
    }
    if constexpr (sizeof(OutT) == 2) {
        // ---- bf16 epilogue: acc -> LDS [128][136] -> 16B global stores ----
        #pragma unroll
        for (int nf = 0; nf < 4; ++nf) {
            int col = wn * 64 + nf * 16 + (lane & 15);
            int gcol = n0 + col;
            float bv = bias[gcol];
            #pragma unroll
            for (int mf = 0; mf < 4; ++mf) {
                #pragma unroll
                for (int r = 0; r < 4; ++r) {
                    int row = wm * 64 + mf * 16 + (lane >> 4) * 4 + r;
                    float v = acc[mf][nf][r] + bv;
                    if (EPI == 0) { if (gcol < 128) v *= 0.17677669529663689f; }
                    else if (EPI == 2) { v = gelu_tanh(v); }
                    smem[row * 136 + col] = f2bs(v);
                }
            }
        }
        __syncthreads();
        #pragma unroll
        for (int p = 0; p < 8; ++p) {
            int row = p * 16 + (t >> 4);
            int c0 = (t & 15) * 8;
            uint4 val = *reinterpret_cast<const uint4*>(&smem[row * 136 + c0]);
            *reinterpret_cast<uint4*>(out + (size_t)(m0 + row) * Ncols + n0 + c0) = val;
        }
    } else {
        // ---- fp32 epilogue (EPI==3): + bias + bf16 residual, direct stores ----
        #pragma unroll
        for (int mf = 0; mf < 4; ++mf) {
            #pragma unroll
            for (int nf = 0; nf < 4; ++nf) {
                int col = n0 + wn * 64 + nf * 16 + (lane & 15);
                float bvv = bias[col];
                #pragma unroll
                for (int r = 0; r < 4; ++r) {
                    size_t row = m0 + wm * 64 + mf * 16 + (lane >> 4) * 4 + r;
                    float v = acc[mf][nf][r] + bvv;
                    if (EPI == 3) v += b2f(res[row * 128 + col]);
                    out[row * Ncols + col] = v;
                }
            }
        }
    }
}

// ---------------- proj GEMM + window-reverse + residual + LN2 fused ----------------
__global__ __launch_bounds__(256) void k_proj_fused(const short* __restrict__ A,
                                                    const short* __restrict__ Bw,
                                                    const float* __restrict__ bias,
                                                    const float* __restrict__ x,
                                                    const float* __restrict__ g,
                                                    const float* __restrict__ bta,
                                                    bf16* __restrict__ x1,
                                                    bf16* __restrict__ xn2) {
    __shared__ __align__(16) short smem[128 * 136];
    short* sA = smem;
    short* sB = smem + 8192;
    int t = threadIdx.x;
    int lane = t & 63, wid = t >> 6;
    int wm = wid >> 1, wn = wid & 1;
    int rsub = lane >> 3, csl = lane & 7;
    int m0 = blockIdx.x * 128;
    float4v acc[4][4];
    #pragma unroll
    for (int a = 0; a < 4; ++a)
        #pragma unroll
        for (int b = 0; b < 4; ++b) acc[a][b] = (float4v){0.f, 0.f, 0.f, 0.f};

    for (int k0 = 0; k0 < 128; k0 += 64) {
        #pragma unroll
        for (int v = 0; v < 4; ++v) {
            int row = (wid * 4 + v) * 8 + rsub;
            int ch = csl ^ (row & 7);
            gload16(A + (size_t)(m0 + row) * 128 + k0 + ch * 8, sA + (wid * 4 + v) * 512);
            gload16(Bw + (size_t)row * 128 + k0 + ch * 8, sB + (wid * 4 + v) * 512);
        }
        __syncthreads();
        #pragma unroll
        for (int kk = 0; kk < 2; ++kk) {
            int crb = kk * 4 + (lane >> 4);
            short8 af[4], bfr[4];
            #pragma unroll
            for (int mf = 0; mf < 4; ++mf) {
                int row = wm * 64 + mf * 16 + (lane & 15);
                af[mf] = *reinterpret_cast<const short8*>(&sA[row * 64 + (crb ^ (row & 7)) * 8]);
            }
            #pragma unroll
            for (int nf = 0; nf < 4; ++nf) {
                int row = wn * 64 + nf * 16 + (lane & 15);
                bfr[nf] = *reinterpret_cast<const short8*>(&sB[row * 64 + (crb ^ (row & 7)) * 8]);
            }
            #pragma unroll
            for (int mf = 0; mf < 4; ++mf)
                #pragma unroll
                for (int nf = 0; nf < 4; ++nf)
                    acc[mf][nf] = mfma16(af[mf], bfr[nf], acc[mf][nf]);
        }
        __syncthreads();
    }

    int*   tokmap = (int*)smem;
    float* psum   = (float*)(smem + 256);
    float* psq    = (float*)(smem + 768);
    if (t < 128) {
        int wr2 = m0 + t;
        int win = wr2 / 98, n = wr2 - win * 98;
        int bb = win >> 8, rem = win & 255;
        int dblk = rem >> 6, hblk = (rem >> 3) & 7, wblk = rem & 7;
        int wd = n / 49, r49 = n - wd * 49, wh = r49 / 7, ww = r49 - wh * 7;
        int d = dblk * 2 + wd, h = hblk * 7 + wh, w = wblk * 7 + ww;
        int dd = d + 1;  if (dd >= 8)  dd -= 8;
        int hh = h + 3;  if (hh >= 56) hh -= 56;
        int w2 = w + 3;  if (w2 >= 56) w2 -= 56;
        tokmap[t] = ((bb * 8 + dd) * 56 + hh) * 56 + w2;
    }
    __syncthreads();

    #pragma unroll
    for (int mf = 0; mf < 4; ++mf) {
        #pragma unroll
        for (int r = 0; r < 4; ++r) {
            int row = wm * 64 + mf * 16 + (lane >> 4) * 4 + r;
            int tok = tokmap[row];
            float s = 0.f, sq = 0.f;
            #pragma unroll
            for (int nf = 0; nf < 4; ++nf) {
                int col = wn * 64 + nf * 16 + (lane & 15);
                float vv = acc[mf][nf][r] + bias[col] + x[(size_t)tok * 128 + col];
                acc[mf][nf][r] = vv;
                s += vv; sq += vv * vv;
            }
            #pragma unroll
            for (int m = 1; m <= 8; m <<= 1) { s += __shfl_xor(s, m); sq += __shfl_xor(sq, m); }
            if ((lane & 15) == 0) { psum[row * 2 + wn] = s; psq[row * 2 + wn] = sq; }
        }
    }
    __syncthreads();
    #pragma unroll
    for (int mf = 0; mf < 4; ++mf) {
        #pragma unroll
        for (int r = 0; r < 4; ++r) {
            int row = wm * 64 + mf * 16 + (lane >> 4) * 4 + r;
            int tok = tokmap[row];
            float s  = psum[row * 2] + psum[row * 2 + 1];
            float sq = psq[row * 2]  + psq[row * 2 + 1];
            float mean = s * (1.0f / 128.0f);
            float var  = sq * (1.0f / 128.0f) - mean * mean;
            float inv  = rsqrtf(var + 1e-5f);
            #pragma unroll
            for (int nf = 0; nf < 4; ++nf) {
                int col = wn * 64 + nf * 16 + (lane & 15);
                float vv = acc[mf][nf][r];
                x1[(size_t)tok * 128 + col] = __float2bfloat16(vv);
                xn2[(size_t)tok * 128 + col] = __float2bfloat16((vv - mean) * inv * g[col] + bta[col]);
            }
        }
    }
}

// ---------------- K3: MFMA window attention (biasT + maskT added on the fly) ----------------
__global__ __launch_bounds__(256, 4) void k_attn_mfma(const bf16* __restrict__ qkv,
                                                      const short* __restrict__ biasT,
                                                      const short* __restrict__ maskT,
                                                      bf16* __restrict__ aout) {
    constexpr int QP = 40;
    constexpr int VP = 136;
    constexpr int PP = 136;
    __shared__ __align__(16) char smem[8704 + 30464];
    short* sVT = (short*)smem;
    short* sQ  = (short*)(smem + 8704);
    short* sK  = (short*)(smem + 8704 + 8960);
    short* sP  = (short*)(smem + 8704);
    int t = threadIdx.x, lane = t & 63, wid = t >> 6;
    int win = blockIdx.x >> 2, head = blockIdx.x & 3;
    const bf16* base = qkv + (size_t)win * Nc * 384 + head * 32;

    for (int idx = t; idx < Nc * 4; idx += 256) {
        int i = idx >> 2, g = idx & 3;
        uint4 q4 = *reinterpret_cast<const uint4*>(base + (size_t)i * 384 + g * 8);
        uint4 k4 = *reinterpret_cast<const uint4*>(base + (size_t)i * 384 + 128 + g * 8);
        uint4 v4 = *reinterpret_cast<const uint4*>(base + (size_t)i * 384 + 256 + g * 8);
        *reinterpret_cast<uint4*>(&sQ[i * QP + g * 8]) = q4;
        *reinterpret_cast<uint4*>(&sK[i * QP + g * 8]) = k4;
        const short* vp = reinterpret_cast<const short*>(&v4);
        #pragma unroll
        for (int e = 0; e < 8; ++e) sVT[(g * 8 + e) * VP + i] = vp[e];
    }
    for (int idx = t; idx < 14 * QP; idx += 256) {
        int r = 98 + idx / QP, c = idx % QP;
        sQ[r * QP + c] = 0; sK[r * QP + c] = 0;
    }
    for (int idx = t; idx < 32 * 30; idx += 256) {
        int d = idx / 30, c = 98 + idx % 30;
        sVT[d * VP + c] = 0;
    }
    __syncthreads();

    float4v s[2][7];
    #pragma unroll
    for (int mi = 0; mi < 2; ++mi)
        #pragma unroll
        for (int fn = 0; fn < 7; ++fn) s[mi][fn] = (float4v){0.f, 0.f, 0.f, 0.f};
    short8 qf[2];
    #pragma unroll
    for (int mi = 0; mi < 2; ++mi) {
        if (wid * 2 + mi < 7) {
            int row = (wid * 2 + mi) * 16 + (lane & 15);
            qf[mi] = *reinterpret_cast<const short8*>(&sQ[row * QP + (lane >> 4) * 8]);
        }
    }
    #pragma unroll
    for (int fn = 0; fn < 7; ++fn) {
        short8 kf = *reinterpret_cast<const short8*>(&sK[(fn * 16 + (lane & 15)) * QP + (lane >> 4) * 8]);
        #pragma unroll
        for (int mi = 0; mi < 2; ++mi) {
            if (wid * 2 + mi < 7) s[mi][fn] = mfma16(qf[mi], kf, s[mi][fn]);
        }
    }

    const unsigned short* bT = (const unsigned short*)(biasT + (size_t)head * 12544);
    const unsigned short* mT = (const unsigned short*)(maskT + (size_t)(win & 255) * 12544);
    #pragma unroll
    for (int mi = 0; mi < 2; ++mi) {
        if (wid * 2 + mi >= 7) continue;
        int i0 = (wid * 2 + mi) * 16 + (lane >> 4) * 4;
        #pragma unroll
        for (int fn = 0; fn < 7; ++fn) {
            int j = fn * 16 + (lane & 15);
            ushort4v b4 = *reinterpret_cast<const ushort4v*>(bT + j * 112 + i0);
            ushort4v m4 = *reinterpret_cast<const ushort4v*>(mT + j * 112 + i0);
            #pragma unroll
            for (int r = 0; r < 4; ++r) {
                s[mi][fn][r] = __expf(s[mi][fn][r] + us2f(b4[r]) + us2f(m4[r]));
            }
        }
        #pragma unroll
        for (int r = 0; r < 4; ++r) {
            float sum = 0.f;
            #pragma unroll
            for (int fn = 0; fn < 7; ++fn) sum += s[mi][fn][r];
            #pragma unroll
            for (int m = 1; m <= 8; m <<= 1) sum += __shfl_xor(sum, m);
            float inv = 1.0f / sum;
            #pragma unroll
            for (int fn = 0; fn < 7; ++fn) s[mi][fn][r] *= inv;
        }
    }
    __syncthreads();

    for (int idx = t; idx < 112 * 16; idx += 256) {
        int rr = idx >> 4, c2 = 112 + (idx & 15);
        sP[rr * PP + c2] = 0;
    }
    #pragma unroll
    for (int mi = 0; mi < 2; ++mi) {
        if (wid * 2 + mi >= 7) continue;
        int i0 = (wid * 2 + mi) * 16 + (lane >> 4) * 4;
        #pragma unroll
        for (int r = 0; r < 4; ++r) {
            #pragma unroll
            for (int fn = 0; fn < 7; ++fn) {
                int j = fn * 16 + (lane & 15);
                sP[(i0 + r) * PP + j] = f2bs(s[mi][fn][r]);
            }
        }
    }
    __syncthreads();

    float4v o[2][2];
    #pragma unroll
    for (int mi = 0; mi < 2; ++mi)
        #pragma unroll
        for (int nd = 0; nd < 2; ++nd) o[mi][nd] = (float4v){0.f, 0.f, 0.f, 0.f};
    #pragma unroll
    for (int jc = 0; jc < 4; ++jc) {
        short8 pf[2];
        #pragma unroll
        for (int mi = 0; mi < 2; ++mi) {
            if (wid * 2 + mi < 7) {
                int row = (wid * 2 + mi) * 16 + (lane & 15);
                pf[mi] = *reinterpret_cast<const short8*>(&sP[row * PP + jc * 32 + (lane >> 4) * 8]);
            }
        }
        #pragma unroll
        for (int nd = 0; nd < 2; ++nd) {
            short8 vf = *reinterpret_cast<const short8*>(&sVT[(nd * 16 + (lane & 15)) * VP + jc * 32 + (lane >> 4) * 8]);
            #pragma unroll
            for (int mi = 0; mi < 2; ++mi) {
                if (wid * 2 + mi < 7) o[mi][nd] = mfma16(pf[mi], vf, o[mi][nd]);
            }
        }
    }
    bf16* obase = aout + (size_t)win * Nc * 128 + head * 32;
    #pragma unroll
    for (int mi = 0; mi < 2; ++mi) {
        if (wid * 2 + mi >= 7) continue;
        #pragma unroll
        for (int nd = 0; nd < 2; ++nd) {
            int d = nd * 16 + (lane & 15);
            #pragma unroll
            for (int r = 0; r < 4; ++r) {
                int i = (wid * 2 + mi) * 16 + (lane >> 4) * 4 + r;
                if (i < 98) obase[(size_t)i * 128 + d] = __float2bfloat16(o[mi][nd][r]);
            }
        }
    }
}

extern "C" void kernel_launch(void* const* d_in, const int* in_sizes, int n_in,
                              void* d_out, int out_size, void* d_ws, size_t ws_size,
                              hipStream_t stream) {
    const float* x      = (const float*)d_in[0];
    const float* mask   = (const float*)d_in[1];
    const int*   relidx = (const int*)  d_in[2];
    const float* n1g    = (const float*)d_in[3];
    const float* n1b    = (const float*)d_in[4];
    const float* qkv_w  = (const float*)d_in[5];
    const float* qkv_b  = (const float*)d_in[6];
    const float* rpb    = (const float*)d_in[7];
    const float* proj_w = (const float*)d_in[8];
    const float* proj_b = (const float*)d_in[9];
    const float* n2g    = (const float*)d_in[10];
    const float* n2b    = (const float*)d_in[11];
    const float* fc1_w  = (const float*)d_in[12];
    const float* fc1_b  = (const float*)d_in[13];
    const float* fc2_w  = (const float*)d_in[14];
    const float* fc2_b  = (const float*)d_in[15];

    char* ws = (char*)d_ws;
    const size_t MB = 1024 * 1024;
    bf16*  xw    = (bf16*)(ws);                // [0, 24.5)    pre -> qkvG
    bf16*  qkv   = (bf16*)(ws + 25 * MB);      // [25, 98.5)   qkvG -> attn
    bf16*  aout  = (bf16*)(ws + 99 * MB);      // [99, 123.5)  attn -> proj_fused
    short* maskT = (short*)(ws + 149 * MB);    // [149, 155.2) pre -> attn
    short* biasT = (short*)(ws + 156 * MB);    // [156, 156.1) pre -> attn
    bf16*  x1    = (bf16*)(ws);                // [0, 24.5)    proj_fused -> fc2 (xw dead; bf16)
    bf16*  xn2   = (bf16*)(ws + 50 * MB);      // [50, 74.5)   proj_fused -> fc1
    bf16*  h1    = (bf16*)(ws + 75 * MB);      // [75, 173)    fc1 -> fc2 (aout/maskT/biasT dead)
    short* wbf   = (short*)(ws + 174 * MB);    // [174, 174.4) whole launch
    float* out   = (float*)d_out;

    const short* wq = wbf;
    const short* wp = wbf + 49152;
    const short* w1 = wbf + 65536;
    const short* w2 = wbf + 131072;

    k_pre<<<PRE_WCONV + PRE_BIAST + PRE_MASKT + PRE_LN1, 256, 0, stream>>>(
        qkv_w, proj_w, fc1_w, fc2_w, wbf,
        relidx, rpb, mask, biasT, maskT,
        x, n1g, n1b, xw);
    k_gemm_mfma<128, 0, bf16, true><<<dim3(3, NTOK / 128), 256, 0, stream>>>((const short*)xw, wq, qkv_b, nullptr, qkv, 384);
    k_attn_mfma<<<BNc * 4, 256, 0, stream>>>(qkv, biasT, maskT, aout);
    k_proj_fused<<<NTOK / 128, 256, 0, stream>>>((const short*)aout, wp, proj_b, x, n2g, n2b, x1, xn2);
    k_gemm_mfma<128, 2, bf16, true><<<dim3(4, NTOK / 128), 256, 0, stream>>>((const short*)xn2, w1, fc1_b, nullptr, h1, 512);
    k_gemm_mfma<512, 3, float, false><<<dim3(NTOK / 128, 1), 256, 0, stream>>>((const short*)h1, w2, fc2_b, x1, out, 128);
}